// Round 7
// baseline (689.436 us; speedup 1.0000x reference)
//
#include <hip/hip_runtime.h>
#include <hip/hip_bf16.h>

#define BB 32
#define CC 64
#define NN 307
#define TT 24
#define CO 192
#define NT (NN*TT)   // 7368
#define GO 1536      // CC*TT

using bf16 = __hip_bfloat16;
typedef __attribute__((ext_vector_type(8))) short bf16x8;
typedef __attribute__((ext_vector_type(4))) float f32x4;

// fp32 weight-arena offsets (element = float)
#define OFF_ln_g   0
#define OFF_ln_b   24
#define OFF_res_W  48
#define OFF_res_b  12336
#define OFF_ca_W1  12528
#define OFF_ca_W2  12552
#define OFF_ca_W3  19920
#define OFF_cc_W   20227
#define OFF_cc_b   24323
#define OFF_ta_W1  24387
#define OFF_ta_W2  24694
#define OFF_ta_W3  44342
#define OFF_tc_W0  44406
#define OFF_tc_b0  52598
#define OFF_tc_W1  52662
#define OFF_tc_b1  60854
#define OFF_ga_W1  60918
#define OFF_ga_W2  60942
#define OFF_ga_W3  62478
#define OFF_g_W    62542
#define W_TOTAL    66638

__device__ __forceinline__ float xload(const void* p, size_t i, int f) {
  return f ? ((const float*)p)[i] : __bfloat162float(((const bf16*)p)[i]);
}
__device__ __forceinline__ void ostore(void* p, size_t i, float v, int f) {
  if (f) ((float*)p)[i] = v; else ((bf16*)p)[i] = __float2bfloat16(v);
}
__device__ __forceinline__ float oload(const void* p, size_t i, int f) {
  return f ? ((const float*)p)[i] : __bfloat162float(((const bf16*)p)[i]);
}

__global__ void MEAM_44787918963464_kernel() {}

// ---- 0b. convert all small weights to fp32 arena (inline dtype probe from p0 = ln_g)
__global__ __launch_bounds__(256) void k_cvt_w(
    const void* p0, const void* p1, const void* p2, const void* p3,
    const void* p4, const void* p5, const void* p6, const void* p7,
    const void* p8, const void* p9, const void* p10, const void* p11,
    const void* p12, const void* p13, const void* p14, const void* p15,
    const void* p16, const void* p17, const void* p18, const void* p19,
    int* flagp, float* dst) {
  int i = blockIdx.x*256 + threadIdx.x;
  unsigned w0 = *(const unsigned*)p0;
  int f = (w0 == 0x3F800000u) ? 1 : 0;
  if (i == 0) *flagp = f;
  if (i >= W_TOTAL) return;
  const void* ps[20] = {p0,p1,p2,p3,p4,p5,p6,p7,p8,p9,p10,p11,p12,p13,p14,p15,p16,p17,p18,p19};
  const int sz[20] = {24,24,12288,192,24,7368,307,4096,64,307,19648,64,8192,64,8192,64,24,1536,64,4096};
  int s = 0, base = 0;
  while (i >= base + sz[s]) { base += sz[s]; s++; }
  dst[i] = f ? ((const float*)ps[s])[i-base]
             : __bfloat162float(((const bf16*)ps[s])[i-base]);
}

// ---- 0cd. merged prep: blocks 0..15 -> composed t-branch conv mats; rest -> Apre
__global__ __launch_bounds__(256) void k_prep_w(const float* __restrict__ W,
    const float* __restrict__ Mc, bf16* __restrict__ Ag, float* __restrict__ tb_bias,
    bf16* __restrict__ Apre) {
  if (blockIdx.x < 16) {
    int g = blockIdx.x*256 + threadIdx.x;
    if (g >= CC*CC) return;
    int pI = g >> 6, c = g & 63;
    const float* W0 = W + OFF_tc_W0;
    const float* b0 = W + OFF_tc_b0;
    const float* W1 = W + OFF_tc_W1;
    const float* b1 = W + OFF_tc_b1;
    const float* resW = W + OFF_res_W;
    const float* resb = W + OFF_res_b;
    float m0=0.f,m1=0.f,m2=0.f,m3=0.f, bb0=0.f, bb2=0.f;
    for (int o=0;o<CC;o++){
      float a1v = W1[(pI*CC+o)*2], b1v = W1[(pI*CC+o)*2+1];
      float a0v = W0[(o*CC+c)*2],  b0v = W0[(o*CC+c)*2+1];
      m0 += b1v*b0v; m1 += b1v*a0v; m2 += a1v*b0v; m3 += a1v*a0v;
      bb0 += b1v*b0[o]; bb2 += a1v*b0[o];
    }
    Ag[pI*320 + 0*64 + c] = __float2bfloat16(m0);
    Ag[pI*320 + 1*64 + c] = __float2bfloat16(m1);
    Ag[pI*320 + 2*64 + c] = __float2bfloat16(m2);
    Ag[pI*320 + 3*64 + c] = __float2bfloat16(m3);
    Ag[pI*320 + 4*64 + c] = __float2bfloat16(resW[(64+pI)*CC + c]);
    if (c == 0){
      tb_bias[pI]    = b1[pI] + bb0 + resb[64+pI];
      tb_bias[64+pI] = bb2;
    }
  } else {
    int idx = (blockIdx.x-16)*256 + threadIdx.x;
    if (idx >= BB*192*128) return;
    int b = idx / 24576;
    int rem = idx - b*24576;
    int p2 = rem >> 7, k = rem & 127;
    const float* resW = W + OFF_res_W;
    const float* gW   = W + OFF_g_W;
    float v;
    if (p2 < 64)       v = (k < 64) ? Mc[b*CC*CC + p2*CC + k] : resW[p2*CC + (k-64)];
    else if (p2 < 128) v = (k < 64) ? gW[(p2-64)*CC + k] : 0.f;
    else               v = (k < 64) ? 0.f : resW[p2*CC + (k-64)];
    Apre[idx] = __float2bfloat16(v);
  }
}

// ---- 1. FUSED LN + per-(b,c,t) reductions. One block per (b,c).
__global__ __launch_bounds__(256) void k_lnct(const void* __restrict__ x, const int* flagp,
    const float* __restrict__ W,
    float* __restrict__ mu_a, float* __restrict__ rs_a,
    float* __restrict__ xw1c, float* __restrict__ xw1g,
    float* __restrict__ lhsc, float* __restrict__ rhsc, float* __restrict__ xw1t) {
  int bc = blockIdx.x;            // (b*CC + c)
  int tid = threadIdx.x;
  int f = *flagp;
  const float* lng  = W + OFF_ln_g;
  const float* lnb  = W + OFF_ln_b;
  const float* caW1 = W + OFF_ca_W1;
  const float* gaW1 = W + OFF_ga_W1;
  const float* caW2 = W + OFF_ca_W2;
  const float* caW3 = W + OFF_ca_W3;
  const float* taW1 = W + OFF_ta_W1;
  __shared__ float xs[NN*25];     // 30.7KB, row-padded
  __shared__ float mus[NN], rss[NN], w1c[NN];
  __shared__ float red[3*240];
  size_t base = (size_t)bc * NT;
  if (f) {
    const float4* xp = (const float4*)((const float*)x + base);
    for (int e=tid; e<NT/4; e+=256){
      float4 q = xp[e];
      int n = e/6; int t0 = e*4 - n*24;
      float* d = &xs[n*25 + t0];
      d[0]=q.x; d[1]=q.y; d[2]=q.z; d[3]=q.w;
    }
  } else {
    const uint4* xp = (const uint4*)((const unsigned short*)x + base);
    for (int e=tid; e<NT/8; e+=256){
      uint4 q = xp[e]; unsigned u[4]={q.x,q.y,q.z,q.w};
      int n = e/3; int t0 = e*8 - n*24;
      float* d = &xs[n*25 + t0];
      #pragma unroll
      for (int k=0;k<4;k++){
        union{unsigned uu;float fl;} lo,hi;
        lo.uu=u[k]<<16; hi.uu=u[k]&0xffff0000u;
        d[k*2]=lo.fl; d[k*2+1]=hi.fl;
      }
    }
  }
  __syncthreads();
  for (int n=tid; n<NN; n+=256){
    const float* row = &xs[n*25];
    float mu=0.f;
    #pragma unroll
    for (int t=0;t<TT;t++) mu += row[t];
    mu *= (1.f/TT);
    float var=0.f;
    #pragma unroll
    for (int t=0;t<TT;t++){ float d=row[t]-mu; var += d*d; }
    var *= (1.f/TT);
    float rs = rsqrtf(var+1e-5f);
    float s1=0.f, s2=0.f;
    #pragma unroll
    for (int t=0;t<TT;t++){
      float hv=(row[t]-mu)*rs*lng[t]+lnb[t];
      s1+=hv*caW1[t]; s2+=hv*gaW1[t];
    }
    mus[n]=mu; rss[n]=rs; w1c[n]=s1;
    int gi = bc*NN+n;
    mu_a[gi]=mu; rs_a[gi]=rs; xw1c[gi]=s1; xw1g[gi]=s2;
  }
  __syncthreads();
  int t = tid % TT, g = tid / TT;   // 10 full n-groups (g<10)
  if (g < 10){
    float gt=lng[t], bt=lnb[t];
    float l=0.f, rr=0.f, xt=0.f;
    for (int n=g; n<NN; n+=10){
      float hv=(xs[n*25+t]-mus[n])*rss[n]*gt+bt;
      l += w1c[n]*caW2[n*TT+t];
      rr+= caW3[n]*hv;
      xt+= taW1[n]*hv;
    }
    red[g*TT+t]=l; red[240+g*TT+t]=rr; red[480+g*TT+t]=xt;
  }
  __syncthreads();
  if (tid < TT){
    float L=0.f,R=0.f,X=0.f;
    #pragma unroll
    for (int g2=0; g2<10; g2++){
      L+=red[g2*TT+tid]; R+=red[240+g2*TT+tid]; X+=red[480+g2*TT+tid];
    }
    lhsc[bc*TT+tid]=L; rhsc[bc*TT+tid]=R; xw1t[bc*TT+tid]=X;
  }
}

// ---- 3. per (b,n,t): rhs_t, rhs_g, lhs_g (reduce over c)
__global__ __launch_bounds__(256) void k_prep_bn(const void* __restrict__ x, const int* flagp,
    const float* __restrict__ mu_a, const float* __restrict__ rs_a,
    const float* __restrict__ W, const float* __restrict__ xw1g,
    float* __restrict__ rhst, float* __restrict__ rhsg, float* __restrict__ lhsg) {
  int i = blockIdx.x*256 + threadIdx.x;     // (b*N+n)*T + t
  if (i >= BB*NN*TT) return;
  int f = *flagp;
  const float* lng  = W + OFF_ln_g;
  const float* lnb  = W + OFF_ln_b;
  const float* taW3 = W + OFF_ta_W3;
  const float* gaW3 = W + OFF_ga_W3;
  const float* gaW2 = W + OFF_ga_W2;
  int t = i % TT; int n = (i/TT)%NN; int b = i/(NN*TT);
  float gt = lng[t], bt = lnb[t];
  float a=0.f,c2=0.f,d=0.f;
  for (int c=0;c<CC;c++){
    int row = (b*CC+c)*NN + n;
    float hv = (xload(x, (size_t)row*TT+t, f) - mu_a[row]) * rs_a[row] * gt + bt;
    a  += taW3[c]*hv;
    c2 += gaW3[c]*hv;
    d  += xw1g[row]*gaW2[c*TT+t];
  }
  rhst[i]=a; rhsg[i]=c2; lhsg[i]=d;
}

// ---- 5+6. merged channel (y=0) + temporal (y=1) attention. grid (BB, 2).
//   y=1 uses reassociation: scores[t,s] = sum_c xw1t[c,t] * (sum_n taW2[c,n]*rhst[n,s])
__global__ __launch_bounds__(256) void k_att_ct(const float* __restrict__ lhsc,
    const float* __restrict__ rhsc, const float* __restrict__ xw1t,
    const float* __restrict__ rhst, const float* __restrict__ W,
    float* __restrict__ Mc, float* __restrict__ attt) {
  int b = blockIdx.x; int tid = threadIdx.x;
  __shared__ float shm[11200];   // 44.8KB, unioned
  if (blockIdx.y == 0) {
    const float* ccW = W + OFF_cc_W;
    float* lc = shm;            // 1536
    float* rc = shm + 1536;     // 1536
    float* sc = shm + 3072;     // 64*65 = 4160
    for (int e=tid;e<CC*TT;e+=256){
      lc[e]=lhsc[b*CC*TT+e];
      rc[e]=rhsc[b*CC*TT+e];
    }
    __syncthreads();
    for (int e=tid;e<CC*CC;e+=256){
      int c=e>>6, d=e&63; float s=0.f;
      for (int t=0;t<TT;t++) s += lc[c*TT+t]*rc[d*TT+t];
      sc[c*(CC+1)+d]=s;
    }
    __syncthreads();
    if (tid<CC){
      float mx=-1e30f;
      for (int d=0;d<CC;d++) mx=fmaxf(mx, sc[tid*(CC+1)+d]);
      float sum=0.f;
      for (int d=0;d<CC;d++){ float e2=__expf(sc[tid*(CC+1)+d]-mx); sc[tid*(CC+1)+d]=e2; sum+=e2; }
      float inv=1.f/sum;
      for (int d=0;d<CC;d++) sc[tid*(CC+1)+d]*=inv;
    }
    __syncthreads();
    for (int e=tid;e<CC*CC;e+=256){
      int o=e>>6, d=e&63; float acc=0.f;
      for (int c=0;c<CC;c++) acc += ccW[o*CC+c]*sc[c*(CC+1)+d];
      Mc[b*CC*CC+e]=acc;
    }
  } else {
    const float* taW2 = W + OFF_ta_W2;
    float* rs2 = shm;             // 7368
    float* xw  = shm + 7368;      // 1536
    float* P   = shm + 8904;      // 1536
    float* sc2 = shm + 10440;     // 576
    for (int e=tid;e<NN*TT;e+=256) rs2[e]=rhst[b*NN*TT+e];
    for (int e=tid;e<CC*TT;e+=256) xw[e]=xw1t[b*CC*TT+e];
    __syncthreads();
    // P[c,s] = sum_n taW2[c,n]*rs2[n,s]
    for (int e=tid;e<CC*TT;e+=256){
      int c=e/TT, s=e-(e/TT)*TT;
      const float* tw = taW2 + c*NN;
      float acc=0.f;
      for (int n=0;n<NN;n++) acc += tw[n]*rs2[n*TT+s];
      P[c*TT+s]=acc;
    }
    __syncthreads();
    // scores[t,s] = sum_c xw[c,t]*P[c,s]
    for (int e=tid;e<TT*TT;e+=256){
      int t=e/TT, s=e-(e/TT)*TT;
      float acc=0.f;
      for (int c=0;c<CC;c++) acc += xw[c*TT+t]*P[c*TT+s];
      sc2[e]=acc;
    }
    __syncthreads();
    if (tid < TT){
      float mx=-1e30f;
      for (int s=0;s<TT;s++) mx=fmaxf(mx,sc2[tid*TT+s]);
      float sum=0.f;
      for (int s=0;s<TT;s++){ float e=__expf(sc2[tid*TT+s]-mx); sc2[tid*TT+s]=e; sum+=e; }
      float inv=1.f/sum;
      for (int s=0;s<TT;s++) attt[b*TT*TT + tid*TT + s]=sc2[tid*TT+s]*inv;
    }
  }
}

// ---- 7a. fused graph attention: MFMA scores (hi/lo bf16) + adj mask + row softmax -> attgh
//   grid (5 n-tiles, BB). Full 64x320 score panel lives in acc[5][4] VGPRs.
__global__ __launch_bounds__(256) void k_attg(const float* __restrict__ lhsg,
    const float* __restrict__ rhsg, const int* __restrict__ adj,
    bf16* __restrict__ attgh) {
  int nt = blockIdx.x, b = blockIdx.y;
  int n0 = nt*64, tid = threadIdx.x;
  __shared__ unsigned short Lh[64*40], Ll[64*40], Rh[64*40], Rl[64*40];
  for (int e=tid; e<64*24; e+=256){
    int r=e/24, t=e-(e/24)*24;
    int gn=n0+r;
    float lv = (gn<NN)? lhsg[((size_t)b*NN+gn)*TT+t] : 0.f;
    bf16 lh=__float2bfloat16(lv); float lhf=__bfloat162float(lh);
    bf16 llo=__float2bfloat16(lv-lhf);
    Lh[r*40+t]=*(unsigned short*)&lh; Ll[r*40+t]=*(unsigned short*)&llo;
  }
  for (int e=tid; e<64*8; e+=256){
    int r=e>>3, t=24+(e&7);
    Lh[r*40+t]=0; Ll[r*40+t]=0;
  }
  int lane=tid&63, w=tid>>6, q=lane>>4, lr=lane&15;
  f32x4 z4={0.f,0.f,0.f,0.f};
  f32x4 acc[5][4];
  #pragma unroll
  for (int mt=0;mt<5;mt++)
    #pragma unroll
    for (int ct=0;ct<4;ct++) acc[mt][ct]=z4;
  bf16x8 ah, al;
  for (int mt=0; mt<5; mt++){
    __syncthreads();
    int m0 = mt*64;
    for (int e=tid; e<64*24; e+=256){
      int r=e/24, t=e-(e/24)*24;
      int gm=m0+r;
      float rv = (gm<NN)? rhsg[((size_t)b*NN+gm)*TT+t] : 0.f;
      bf16 rh=__float2bfloat16(rv); float rhf=__bfloat162float(rh);
      bf16 rlo=__float2bfloat16(rv-rhf);
      Rh[r*40+t]=*(unsigned short*)&rh; Rl[r*40+t]=*(unsigned short*)&rlo;
    }
    for (int e=tid; e<64*8; e+=256){
      int r=e>>3, t=24+(e&7);
      Rh[r*40+t]=0; Rl[r*40+t]=0;
    }
    __syncthreads();
    if (mt == 0){
      ah = *(const bf16x8*)&Lh[(w*16+lr)*40 + q*8];
      al = *(const bf16x8*)&Ll[(w*16+lr)*40 + q*8];
    }
    #pragma unroll
    for (int ct=0;ct<4;ct++){
      bf16x8 bh = *(const bf16x8*)&Rh[(ct*16+lr)*40 + q*8];
      bf16x8 bl = *(const bf16x8*)&Rl[(ct*16+lr)*40 + q*8];
      acc[mt][ct]=__builtin_amdgcn_mfma_f32_16x16x32_bf16(ah,bh,acc[mt][ct],0,0,0);
      acc[mt][ct]=__builtin_amdgcn_mfma_f32_16x16x32_bf16(ah,bl,acc[mt][ct],0,0,0);
      acc[mt][ct]=__builtin_amdgcn_mfma_f32_16x16x32_bf16(al,bh,acc[mt][ct],0,0,0);
    }
  }
  // mask + row softmax (rows live across the 16 lr lanes)
  int nrow[4];
  #pragma unroll
  for (int r=0;r<4;r++) nrow[r] = n0 + w*16 + q*4 + r;
  float mx[4] = {-1e30f,-1e30f,-1e30f,-1e30f};
  #pragma unroll
  for (int mt=0;mt<5;mt++){
    #pragma unroll
    for (int ct=0;ct<4;ct++){
      int m = mt*64 + ct*16 + lr;
      #pragma unroll
      for (int r=0;r<4;r++){
        float s = acc[mt][ct][r];
        bool ok = (m < NN) && (nrow[r] < NN) && (adj[nrow[r]*NN + m] > 0);
        s = ok ? s : -1e30f;
        acc[mt][ct][r] = s;
        mx[r] = fmaxf(mx[r], s);
      }
    }
  }
  #pragma unroll
  for (int off=1; off<16; off<<=1)
    #pragma unroll
    for (int r=0;r<4;r++) mx[r] = fmaxf(mx[r], __shfl_xor(mx[r], off));
  float sum[4] = {0.f,0.f,0.f,0.f};
  #pragma unroll
  for (int mt=0;mt<5;mt++)
    #pragma unroll
    for (int ct=0;ct<4;ct++)
      #pragma unroll
      for (int r=0;r<4;r++){
        float s = acc[mt][ct][r];
        float e = (s > -1e29f) ? __expf(s - mx[r]) : 0.f;
        acc[mt][ct][r] = e;
        sum[r] += e;
      }
  #pragma unroll
  for (int off=1; off<16; off<<=1)
    #pragma unroll
    for (int r=0;r<4;r++) sum[r] += __shfl_xor(sum[r], off);
  float inv[4];
  #pragma unroll
  for (int r=0;r<4;r++) inv[r] = 1.f/sum[r];
  #pragma unroll
  for (int mt=0;mt<5;mt++)
    #pragma unroll
    for (int ct=0;ct<4;ct++){
      int m = mt*64 + ct*16 + lr;
      #pragma unroll
      for (int r=0;r<4;r++){
        if (m < NN && nrow[r] < NN)
          attgh[((size_t)b*NN+nrow[r])*NN + m] = __float2bfloat16(acc[mt][ct][r]*inv[r]);
      }
    }
}

// ---- 7b. fused c-branch + residual(0..63) + hg + residual(128..191 -> resg bf16) via MFMA.
__global__ __launch_bounds__(256) void k_hgc_mfma(
    const void* __restrict__ x, const int* flagp,
    const float* __restrict__ mu_a, const float* __restrict__ rs_a,
    const float* __restrict__ W, const bf16* __restrict__ Apre,
    bf16* __restrict__ hg, bf16* __restrict__ resg, void* __restrict__ out) {
  int jt = blockIdx.x, b = blockIdx.y, tid = threadIdx.x;
  int f = *flagp;
  int j0 = jt*64;
  const float* lng = W + OFF_ln_g;
  const float* lnb = W + OFF_ln_b;
  const float* ccb = W + OFF_cc_b;
  const float* resb= W + OFF_res_b;
  __shared__ unsigned short Bs[64*128];   // [j][k] bf16, 16KB

  {
    int c = tid >> 2, jg = tid & 3;
    float xv[16];
    int jbase = j0 + jg*16;
    size_t xoff = (size_t)(b*CC + c)*NT + jbase;
    if (jbase + 15 < NT) {
      if (f) {
        const float4* xp = (const float4*)((const float*)x + xoff);
        #pragma unroll
        for (int v=0; v<4; v++){ float4 q = xp[v]; xv[v*4]=q.x; xv[v*4+1]=q.y; xv[v*4+2]=q.z; xv[v*4+3]=q.w; }
      } else {
        const uint4* xp = (const uint4*)((const unsigned short*)x + xoff);
        #pragma unroll
        for (int v=0; v<2; v++){
          uint4 q = xp[v]; unsigned u[4]={q.x,q.y,q.z,q.w};
          #pragma unroll
          for (int kk2=0;kk2<4;kk2++){
            union{unsigned uu;float fl;} lo,hi;
            lo.uu=u[kk2]<<16; hi.uu=u[kk2]&0xffff0000u;
            xv[v*8+kk2*2]=lo.fl; xv[v*8+kk2*2+1]=hi.fl;
          }
        }
      }
    } else {
      #pragma unroll
      for (int i=0;i<16;i++){ int j=jbase+i; xv[i] = (j<NT)? xload(x, xoff+i, f) : 0.f; }
    }
    const float* mu_r = mu_a + (b*CC+c)*NN;
    const float* rs_r = rs_a + (b*CC+c)*NN;
    #pragma unroll
    for (int i=0;i<16;i++){
      int j = jbase + i;
      int jl = jg*16 + i;
      float hv = 0.f, xf = 0.f;
      if (j < NT){
        int n = j / 24, t = j - n*24;
        xf = xv[i];
        hv = (xf - mu_r[n]) * rs_r[n] * lng[t] + lnb[t];
      }
      int cs = c ^ ((jl&7)<<3);
      bf16 hb = __float2bfloat16(hv), xb = __float2bfloat16(xf);
      Bs[jl*128 + cs]      = *(unsigned short*)&hb;
      Bs[jl*128 + cs + 64] = *(unsigned short*)&xb;
    }
  }

  int lane = tid & 63, w = tid >> 6;
  int q = lane >> 4, lr = lane & 15;
  bf16x8 afo[4], afh[2], afr[2];
  {
    const unsigned short* Ab = (const unsigned short*)Apre + (size_t)b*24576;
    const unsigned short* r0 = Ab + (w*16 + lr)*128;
    #pragma unroll
    for (int kc=0;kc<4;kc++) afo[kc] = *(const bf16x8*)&r0[kc*32 + q*8];
    const unsigned short* r1 = Ab + (64 + w*16 + lr)*128;
    #pragma unroll
    for (int kc=0;kc<2;kc++) afh[kc] = *(const bf16x8*)&r1[kc*32 + q*8];
    const unsigned short* r2 = Ab + (128 + w*16 + lr)*128;
    #pragma unroll
    for (int kc=0;kc<2;kc++) afr[kc] = *(const bf16x8*)&r2[(kc+2)*32 + q*8];
  }
  f32x4 z4 = {0.f,0.f,0.f,0.f};
  f32x4 acco[4] = {z4,z4,z4,z4};
  f32x4 acch[4] = {z4,z4,z4,z4};
  f32x4 accr[4] = {z4,z4,z4,z4};
  __syncthreads();

  #pragma unroll
  for (int ct=0; ct<4; ct++){
    int jl = ct*16 + lr;
    int sw = ((jl&7)<<3);
    #pragma unroll
    for (int kc=0; kc<4; kc++){
      int ke = (kc*32 + q*8) ^ sw;
      bf16x8 bfr = *(const bf16x8*)&Bs[jl*128 + ke];
      acco[ct] = __builtin_amdgcn_mfma_f32_16x16x32_bf16(afo[kc], bfr, acco[ct], 0,0,0);
      if (kc < 2)
        acch[ct] = __builtin_amdgcn_mfma_f32_16x16x32_bf16(afh[kc], bfr, acch[ct], 0,0,0);
      else
        accr[ct] = __builtin_amdgcn_mfma_f32_16x16x32_bf16(afr[kc-2], bfr, accr[ct], 0,0,0);
    }
  }

  #pragma unroll
  for (int ct=0;ct<4;ct++){
    int jl = ct*16 + lr;
    int j = j0 + jl;
    if (j < NT){
      #pragma unroll
      for (int r=0;r<4;r++){
        int p2 = w*16 + q*4 + r;
        float v = acco[ct][r] + ccb[p2] + resb[p2];
        ostore(out, ((size_t)b*CO + p2)*NT + j, fmaxf(v,0.f), f);
      }
      int n = j/24, t2 = j - n*24;
      size_t hb2 = ((size_t)b*NN + n)*GO + t2;
      #pragma unroll
      for (int r=0;r<4;r++){
        int o = w*16 + q*4 + r;
        hg[hb2 + o*TT] = __float2bfloat16(acch[ct][r]);
      }
      #pragma unroll
      for (int r=0;r<4;r++){
        int p3 = w*16 + q*4 + r;
        resg[((size_t)b*CC + p3)*NT + j] = __float2bfloat16(accr[ct][r] + resb[128+p3]);
      }
    }
  }
}

// ---- 7c. graph GEMM, MFMA bf16: out[128+o] = relu(attg@hg + resg)
__global__ __launch_bounds__(256) void k_gemm_g(const bf16* __restrict__ attgh,
    const bf16* __restrict__ hg, const bf16* __restrict__ resg,
    const int* flagp, void* __restrict__ out) {
  int jt = blockIdx.x, nt = blockIdx.y, b = blockIdx.z;
  int tid = threadIdx.x;
  int f = *flagp;
  int n0 = nt*64, j0 = jt*64;
  __shared__ unsigned short As[64*72];
  __shared__ unsigned short Bs[64*72];
  int lane = tid & 63, w = tid >> 6;
  int q = lane >> 4, lr = lane & 15;
  f32x4 z4 = {0.f,0.f,0.f,0.f};
  f32x4 acc[4] = {z4,z4,z4,z4};
  const unsigned short* Ag = (const unsigned short*)attgh + (size_t)b*NN*NN;
  const unsigned short* Bg = (const unsigned short*)hg + (size_t)b*NN*GO;
  for (int m0=0;m0<NN;m0+=64){
    for (int u=tid; u<512; u+=256){
      int r=u>>3, kb=(u&7)*8;
      int gn=n0+r, gm=m0+kb;
      if (gn<NN && gm+7<NN){
        *(uint4*)&As[r*72+kb] = *(const uint4*)&Ag[(size_t)gn*NN + gm];
      } else {
        for (int i2=0;i2<8;i2++){
          int m=gm+i2;
          As[r*72+kb+i2] = (gn<NN && m<NN) ? Ag[(size_t)gn*NN+m] : 0;
        }
      }
    }
    for (int u=tid; u<512; u+=256){
      int m = u>>3, jb = (u&7)*8;       // coalesced: 8 lanes read 128B of row gm
      int gm = m0 + m;
      unsigned short s[8];
      if (gm < NN){
        *(uint4*)s = *(const uint4*)&Bg[(size_t)gm*GO + j0 + jb];
      } else {
        #pragma unroll
        for (int i2=0;i2<8;i2++) s[i2]=0;
      }
      int mb = m>>3, ml2 = m&7;
      #pragma unroll
      for (int i2=0;i2<8;i2++){
        int j = jb + i2;
        int col = ((mb ^ (j>>3)) << 3) | ml2;
        Bs[j*72 + col] = s[i2];
      }
    }
    __syncthreads();
    #pragma unroll
    for (int kk=0;kk<64;kk+=32){
      bf16x8 af = *(const bf16x8*)&As[(w*16+lr)*72 + kk + q*8];
      #pragma unroll
      for (int ct=0;ct<4;ct++){
        int jrow = ct*16+lr;
        int kb = kk + q*8;
        int col = (((kb>>3) ^ (jrow>>3)) << 3);
        bf16x8 bfr = *(const bf16x8*)&Bs[jrow*72 + col];
        acc[ct] = __builtin_amdgcn_mfma_f32_16x16x32_bf16(af, bfr, acc[ct], 0,0,0);
      }
    }
    __syncthreads();
  }
  #pragma unroll
  for (int ct=0;ct<4;ct++){
    #pragma unroll
    for (int r=0;r<4;r++){
      int n = n0 + w*16 + q*4 + r;
      if (n >= NN) continue;
      int j = j0 + ct*16 + lr;
      int o = j/TT, t2 = j%TT;
      size_t idx = ((size_t)b*CO + 128 + o)*NT + (size_t)n*TT + t2;
      float v = acc[ct][r] + __bfloat162float(resg[((size_t)b*CC + o)*NT + (size_t)n*TT + t2]);
      ostore(out, idx, fmaxf(v, 0.f), f);
    }
  }
}

// ---- 8f. FALLBACK c-branch (raw write)
__global__ __launch_bounds__(256) void k_cmix(const float* __restrict__ Mc,
    const void* __restrict__ x, const int* flagp,
    const float* __restrict__ mu_a, const float* __restrict__ rs_a,
    const float* __restrict__ W, void* __restrict__ out) {
  int jt=blockIdx.x, b=blockIdx.y, tid=threadIdx.x;
  int f = *flagp;
  int j0=jt*64;
  const float* lng = W + OFF_ln_g;
  const float* lnb = W + OFF_ln_b;
  const float* ccb = W + OFF_cc_b;
  __shared__ float Ms[CC*64];
  __shared__ float Hs[CC*64];
  for (int e=tid;e<CC*64;e+=256){
    int o=e&63, d=e>>6;
    Ms[e]=Mc[b*CC*CC + o*CC + d];
  }
  for (int e=tid;e<CC*64;e+=256){
    int d=e>>6, j=e&63; int jj=j0+j;
    float hv = 0.f;
    if (jj<NT){
      int n = jj/TT, t = jj%TT;
      int row = (b*CC+d)*NN + n;
      hv = (xload(x, (size_t)(b*CC+d)*NT + jj, f) - mu_a[row]) * rs_a[row] * lng[t] + lnb[t];
    }
    Hs[e]=hv;
  }
  __syncthreads();
  int ti=tid&15, tj=tid>>4;
  float acc[4][4]={};
  for (int d=0;d<CC;d++){
    float4 a4=*(const float4*)&Ms[d*64+ti*4];
    float4 b4=*(const float4*)&Hs[d*64+tj*4];
    float av[4]={a4.x,a4.y,a4.z,a4.w};
    float bv[4]={b4.x,b4.y,b4.z,b4.w};
    for (int i=0;i<4;i++)
      for (int j=0;j<4;j++) acc[i][j]+=av[i]*bv[j];
  }
  for (int i=0;i<4;i++){
    int o=ti*4+i; float bias=ccb[o];
    for (int j=0;j<4;j++){
      int jj=j0+tj*4+j;
      if (jj<NT)
        ostore(out, ((size_t)b*CO+o)*NT+jj, acc[i][j]+bias, f);
    }
  }
}

// ---- 8g. FALLBACK fused g-branch
__global__ __launch_bounds__(256) void k_graph(const float* __restrict__ lhsg,
    const float* __restrict__ rhsg, const int* __restrict__ adj,
    const void* __restrict__ x, const int* flagp,
    const float* __restrict__ mu_a, const float* __restrict__ rs_a,
    const float* __restrict__ W, void* __restrict__ out) {
  int n = blockIdx.x, b = blockIdx.y, tid = threadIdx.x;
  int f = *flagp;
  const float* lng = W + OFF_ln_g;
  const float* lnb = W + OFF_ln_b;
  const float* gW  = W + OFF_g_W;
  __shared__ float ls[TT];
  __shared__ float sv[NN];
  __shared__ float red[256];
  __shared__ float wl[NN];
  __shared__ int   ml[NN];
  __shared__ int   cnt;
  __shared__ float z[CC*TT];
  __shared__ float Gs[CC*CC];
  __shared__ float gs[TT], bs[TT];
  if (tid < TT){
    ls[tid] = lhsg[(b*NN+n)*TT + tid];
    gs[tid] = lng[tid]; bs[tid] = lnb[tid];
  }
  for (int e=tid;e<CC*CC;e+=256) Gs[e]=gW[e];
  __syncthreads();
  float lmax = -1e30f;
  for (int m=tid;m<NN;m+=256){
    float s = -1e30f;
    if (adj[n*NN+m] > 0){
      const float* rr = rhsg + ((size_t)b*NN+m)*TT;
      float acc=0.f;
      for (int t=0;t<TT;t++) acc += ls[t]*rr[t];
      s = acc;
    }
    sv[m]=s; lmax=fmaxf(lmax,s);
  }
  red[tid]=lmax; __syncthreads();
  for (int k=128;k>0;k>>=1){ if (tid<k) red[tid]=fmaxf(red[tid],red[tid+k]); __syncthreads(); }
  float mx = red[0]; __syncthreads();
  float lsum=0.f;
  for (int m=tid;m<NN;m+=256){
    float e = (sv[m] > -1e29f) ? __expf(sv[m]-mx) : 0.f;
    sv[m]=e; lsum+=e;
  }
  red[tid]=lsum; __syncthreads();
  for (int k=128;k>0;k>>=1){ if (tid<k) red[tid]+=red[tid+k]; __syncthreads(); }
  float inv = 1.f/red[0];
  if (tid==0){
    int c=0;
    for (int m=0;m<NN;m++) if (sv[m]!=0.f){ ml[c]=m; wl[c]=sv[m]*inv; c++; }
    cnt=c;
  }
  __syncthreads();
  int K = cnt;
  {
    int c = tid>>2, tg = tid&3;
    float acc[6]={0,0,0,0,0,0};
    float s0 = 0.f;
    const float* mu_r = mu_a + (b*CC+c)*NN;
    const float* rs_r = rs_a + (b*CC+c)*NN;
    size_t xbase = (size_t)(b*CC+c)*NT;
    for (int k=0;k<K;k++){
      int m = ml[k];
      float wr = wl[k]*rs_r[m];
      s0 += wr*mu_r[m];
      size_t xm = xbase + m*TT + tg*6;
      for (int j=0;j<6;j++) acc[j] += wr*xload(x, xm+j, f);
    }
    for (int j=0;j<6;j++){
      int t = tg*6+j;
      z[c*TT+t] = gs[t]*(acc[j]-s0) + bs[t];
    }
  }
  __syncthreads();
  {
    int o = tid>>2, tg = tid&3;
    float acc[6]={0,0,0,0,0,0};
    for (int c=0;c<CC;c++){
      float gwv = Gs[o*CC+c];
      const float* zr = &z[c*TT + tg*6];
      for (int j=0;j<6;j++) acc[j] += gwv*zr[j];
    }
    size_t base = ((size_t)b*CO + 128 + o)*NT + n*TT + tg*6;
    for (int j=0;j<6;j++)
      ostore(out, base+j, acc[j], f);
  }
}

// ---- 9. FALLBACK t-branch
__global__ __launch_bounds__(256) void k_tbranch(const void* __restrict__ x, const int* flagp,
    const float* __restrict__ mu_a, const float* __restrict__ rs_a,
    const float* __restrict__ W, const float* __restrict__ attt,
    void* __restrict__ out, int fuse) {
  int chunk = blockIdx.x, b = blockIdx.y, tid = threadIdx.x;
  int f = *flagp;
  int n0 = chunk*4;
  const float* lng = W + OFF_ln_g;
  const float* lnb = W + OFF_ln_b;
  const float* W0  = W + OFF_tc_W0;
  const float* b0  = W + OFF_tc_b0;
  const float* W1  = W + OFF_tc_W1;
  const float* b1  = W + OFF_tc_b1;
  __shared__ float hs[256*25];
  __shared__ float at[TT*TT];
  for (int e=tid;e<CC*4*TT;e+=256){
    int c=e/(4*TT), rem=e%(4*TT), i=rem/TT, t=rem%TT;
    int n=n0+i;
    float hv=0.f;
    if (n<NN){
      int row=(b*CC+c)*NN+n;
      hv = (xload(x,(size_t)row*TT+t,f) - mu_a[row]) * rs_a[row] * lng[t] + lnb[t];
    }
    hs[(c*4+i)*25+t] = hv;
  }
  for (int e=tid;e<TT*TT;e+=256) at[e]=attt[b*TT*TT+e];
  __syncthreads();
  {
    float r[TT], o2[TT];
    float* myrow = &hs[tid*25];
    #pragma unroll
    for (int s=0;s<TT;s++) r[s]=myrow[s];
    for (int t=0;t<TT;t++){
      float a=0.f;
      #pragma unroll
      for (int s=0;s<TT;s++) a += at[t*TT+s]*r[s];
      o2[t]=a;
    }
    #pragma unroll
    for (int t=0;t<TT;t++) myrow[t]=o2[t];
  }
  __syncthreads();
  {
    int o = tid>>2, i = tid&3;
    float acc[TT];
    float bb = b0[o];
    for (int t=0;t<TT;t++) acc[t]=bb;
    for (int c=0;c<CC;c++){
      float wa = W0[(o*CC+c)*2], wb = W0[(o*CC+c)*2+1];
      const float* row = &hs[(c*4+i)*25];
      acc[0] += wb*row[0];
      #pragma unroll
      for (int t=1;t<TT;t++) acc[t] += wa*row[t-1] + wb*row[t];
    }
    __syncthreads();
    float* myrow = &hs[tid*25];
    #pragma unroll
    for (int t=0;t<TT;t++) myrow[t]=acc[t];
  }
  __syncthreads();
  {
    int o2 = tid>>2, i = tid&3;
    int n = n0+i;
    float acc[TT];
    float bb = b1[o2];
    for (int t=0;t<TT;t++) acc[t]=bb;
    for (int o=0;o<CC;o++){
      float wa = W1[(o2*CC+o)*2], wb = W1[(o2*CC+o)*2+1];
      const float* row = &hs[(o*4+i)*25];
      acc[0] += wb*row[0];
      acc[1] += wb*row[1];
      #pragma unroll
      for (int t=2;t<TT;t++) acc[t] += wa*row[t-2] + wb*row[t];
    }
    if (n<NN){
      size_t base = (((size_t)b*CO + 64 + o2)*NN + n)*TT;
      if (fuse){
        for (int t=0;t<TT;t++){
          float v = acc[t] + oload(out, base+t, f);
          ostore(out, base+t, fmaxf(v,0.f), f);
        }
      } else {
        for (int t=0;t<TT;t++) ostore(out, base+t, acc[t], f);
      }
    }
  }
}

// ---- 9m. t-branch via MFMA: composed 4-tap conv GEMM + fused residual tap, final write.
__device__ __forceinline__ void tb_load_raw(const void* __restrict__ x, int f, int b, int c, int nn,
    float* h) {
  if (nn < NN) {
    size_t off = (size_t)(b*CC + c)*NT + (size_t)nn*TT;
    if (f) {
      const float4* xp = (const float4*)((const float*)x + off);
      #pragma unroll
      for (int v=0; v<6; v++){
        float4 q = xp[v];
        h[v*4+0]=q.x; h[v*4+1]=q.y; h[v*4+2]=q.z; h[v*4+3]=q.w;
      }
    } else {
      const uint4* xp = (const uint4*)((const unsigned short*)x + off);
      #pragma unroll
      for (int v=0; v<3; v++){
        uint4 q = xp[v];
        unsigned wsv[4] = {q.x,q.y,q.z,q.w};
        #pragma unroll
        for (int k=0;k<4;k++){
          union { unsigned u; float fl; } lo, hi;
          lo.u = wsv[k] << 16; hi.u = wsv[k] & 0xffff0000u;
          h[v*8 + k*2] = lo.fl; h[v*8 + k*2 + 1] = hi.fl;
        }
      }
    }
  } else {
    #pragma unroll
    for (int t=0;t<TT;t++) h[t]=0.f;
  }
}

__global__ __launch_bounds__(256) void k_tb_mfma(
    const void* __restrict__ x, const int* flagp,
    const float* __restrict__ mu_a, const float* __restrict__ rs_a,
    const float* __restrict__ W, const float* __restrict__ attt,
    const bf16* __restrict__ Agm, const float* __restrict__ tb_bias,
    void* __restrict__ out) {
  int chunk = blockIdx.x, b = blockIdx.y, tid = threadIdx.x;
  int f = *flagp;
  int n0 = chunk*8;
  const float* lng = W + OFF_ln_g;
  const float* lnb = W + OFF_ln_b;
  __shared__ unsigned short Bs[8*27*64];   // h' [n][s][c], s=t+3, 27648B
  __shared__ unsigned short Xs[8*24*64];   // raw x [n][t][c], 24576B

  for (int e=tid; e<8*3*64; e+=256){
    int n = e/192, rem = e%192, s = rem>>6, cz = rem&63;
    Bs[((n*27+s)<<6) + cz] = 0;
  }

  int c  = tid & 63;
  int nA = tid >> 6;
  float h0[TT], h1[TT];
  tb_load_raw(x, f, b, c, n0+nA,   h0);
  tb_load_raw(x, f, b, c, n0+nA+4, h1);
  #pragma unroll
  for (int t=0;t<TT;t++){
    int cs = c ^ ((t&7)<<3);
    bf16 v0 = __float2bfloat16(h0[t]);
    bf16 v1 = __float2bfloat16(h1[t]);
    Xs[(nA*24+t)*64 + cs]     = *reinterpret_cast<unsigned short*>(&v0);
    Xs[((nA+4)*24+t)*64 + cs] = *reinterpret_cast<unsigned short*>(&v1);
  }
  {
    int nn0 = n0+nA, nn1 = n0+nA+4;
    if (nn0 < NN){
      int r = (b*CC+c)*NN + nn0; float mu = mu_a[r], rs = rs_a[r];
      #pragma unroll
      for (int t=0;t<TT;t++) h0[t] = (h0[t]-mu)*rs*lng[t] + lnb[t];
    }
    if (nn1 < NN){
      int r = (b*CC+c)*NN + nn1; float mu = mu_a[r], rs = rs_a[r];
      #pragma unroll
      for (int t=0;t<TT;t++) h1[t] = (h1[t]-mu)*rs*lng[t] + lnb[t];
    }
  }
  const float* att_b = attt + b*TT*TT;
  for (int t=0;t<TT;t++){
    float a0=0.f, a1=0.f;
    #pragma unroll
    for (int s=0;s<TT;s++){
      float wv = att_b[t*TT+s];
      a0 += wv*h0[s]; a1 += wv*h1[s];
    }
    int sI = t+3;
    int cs = c ^ ((sI&7)<<3);
    bf16 v0 = __float2bfloat16(a0);
    bf16 v1 = __float2bfloat16(a1);
    Bs[((nA*27+sI)<<6) + cs]     = *reinterpret_cast<unsigned short*>(&v0);
    Bs[(((nA+4)*27+sI)<<6) + cs] = *reinterpret_cast<unsigned short*>(&v1);
  }

  int lane = tid & 63, w = tid >> 6;
  int q = lane >> 4, lr = lane & 15;
  bf16x8 af[10];
  const unsigned short* Arow = (const unsigned short*)Agm + (size_t)(w*16+lr)*320;
  #pragma unroll
  for (int kc=0;kc<10;kc++)
    af[kc] = *(const bf16x8*)&Arow[kc*32 + q*8];

  f32x4 z4 = {0.f,0.f,0.f,0.f};
  f32x4 acc[12] = {z4,z4,z4,z4,z4,z4,z4,z4,z4,z4,z4,z4};
  __syncthreads();

  #pragma unroll
  for (int ct=0; ct<12; ct++){
    int col = ct*16 + lr;
    int nl = col/24, t = col - nl*24;
    #pragma unroll
    for (int kc=0;kc<8;kc++){
      int tap = kc>>1;
      int s = t + 3 - tap;
      int cb = ((kc&1)*32 + q*8) ^ ((s&7)<<3);
      bf16x8 bfr = *(const bf16x8*)&Bs[((nl*27+s)<<6) + cb];
      acc[ct] = __builtin_amdgcn_mfma_f32_16x16x32_bf16(af[kc], bfr, acc[ct], 0,0,0);
    }
    #pragma unroll
    for (int kc2=0;kc2<2;kc2++){
      int cb = (kc2*32 + q*8) ^ ((t&7)<<3);
      bf16x8 bfr = *(const bf16x8*)&Xs[(nl*24+t)*64 + cb];
      acc[ct] = __builtin_amdgcn_mfma_f32_16x16x32_bf16(af[8+kc2], bfr, acc[ct], 0,0,0);
    }
  }

  #pragma unroll
  for (int ct=0;ct<12;ct++){
    int col = ct*16 + lr;
    int nl = col/24, t = col - nl*24;
    int nn = n0 + nl;
    if (nn < NN){
      #pragma unroll
      for (int r=0;r<4;r++){
        int pI = w*16 + q*4 + r;
        size_t idx = ((size_t)b*CO + 64 + pI)*NT + (size_t)nn*TT + t;
        float v = acc[ct][r] + tb_bias[pI] + (t>=2 ? tb_bias[64+pI] : 0.f);
        ostore(out, idx, fmaxf(v, 0.f), f);
      }
    }
  }
}

// ---- 10. FALLBACK final: out = relu(out + res_W@x + res_b)
__global__ __launch_bounds__(256) void k_res_final(const void* __restrict__ x, const int* flagp,
    const float* __restrict__ W, void* __restrict__ out) {
  int jt=blockIdx.x, ot=blockIdx.y, b=blockIdx.z; int tid=threadIdx.x;
  int f = *flagp;
  int j0=jt*64, o0=ot*64;
  const float* resW = W + OFF_res_W;
  const float* resb = W + OFF_res_b;
  __shared__ float Ws[CC*64];
  __shared__ float Xs[CC*64];
  for (int e=tid;e<CC*64;e+=256){
    int o=e&63, c=e>>6;
    Ws[e] = resW[(o0+o)*CC + c];
  }
  for (int e=tid;e<CC*64;e+=256){
    int c=e>>6, j=e&63; int jj=j0+j;
    Xs[e] = (jj<NT) ? xload(x, (size_t)(b*CC+c)*NT + jj, f) : 0.f;
  }
  __syncthreads();
  int ti=tid&15, tj=tid>>4;
  float acc[4][4]={};
  for (int k=0;k<CC;k++){
    float4 a4=*(const float4*)&Ws[k*64+ti*4];
    float4 b4=*(const float4*)&Xs[k*64+tj*4];
    float av[4]={a4.x,a4.y,a4.z,a4.w};
    float bv[4]={b4.x,b4.y,b4.z,b4.w};
    for (int i=0;i<4;i++)
      for (int j=0;j<4;j++) acc[i][j]+=av[i]*bv[j];
  }
  for (int i=0;i<4;i++){
    int o=o0+ti*4+i; float bias=resb[o];
    for (int j=0;j<4;j++){
      int jj=j0+tj*4+j;
      if (jj<NT){
        size_t idx=((size_t)b*CO+o)*NT+jj;
        float v = acc[i][j] + bias + oload(out, idx, f);
        ostore(out, idx, fmaxf(v,0.f), f);
      }
    }
  }
}

extern "C" void kernel_launch(void* const* d_in, const int* in_sizes, int n_in,
                              void* d_out, int out_size, void* d_ws, size_t ws_size,
                              hipStream_t stream) {
  const void* x     = d_in[0];
  const int*  adj   = (const int*)d_in[1];
  void* out = d_out;

  float* p = (float*)d_ws;
  int*   flagp = (int*)p; p += 4;
  float* Wf  = p; p += W_TOTAL;
  float* mu_a = p; p += (size_t)BB*CC*NN;
  float* rs_a = p; p += (size_t)BB*CC*NN;
  float* xw1c = p; p += (size_t)BB*CC*NN;
  float* xw1g = p; p += (size_t)BB*CC*NN;
  float* xw1t = p; p += (size_t)BB*CC*TT;
  float* lhsc = p; p += (size_t)BB*CC*TT;
  float* rhsc = p; p += (size_t)BB*CC*TT;
  float* rhst = p; p += (size_t)BB*NN*TT;
  float* rhsg = p; p += (size_t)BB*NN*TT;
  float* lhsg = p; p += (size_t)BB*NN*TT;
  float* attt = p; p += (size_t)BB*TT*TT;
  float* Mc   = p; p += (size_t)BB*CC*CC;
  bf16*  Agm  = (bf16*)p; p += 10240;    // 64*320 bf16 composed conv+res matrices
  float* tb_bias = p; p += 128;          // bias0[64], bias2[64]
  bf16*  Apre = (bf16*)p; p += (size_t)BB*192*128/2;   // [b][192][128] bf16
  bf16*  attgh = (bf16*)p; p += (size_t)BB*NN*NN/2 + 16;
  bf16*  resg = (bf16*)p; p += (size_t)BB*CC*NT/2 + 16; // rows 128..191 residual bf16
  bf16*  hg   = (bf16*)p;
  size_t need = ((char*)(hg + (size_t)BB*NN*GO)) - (char*)d_ws;
  bool gemm_path = (ws_size >= need);

  k_cvt_w<<<dim3((W_TOTAL+255)/256), dim3(256), 0, stream>>>(
      d_in[2], d_in[3], d_in[4], d_in[5], d_in[6], d_in[7], d_in[8], d_in[9],
      d_in[10], d_in[11], d_in[12], d_in[13], d_in[14], d_in[15], d_in[16],
      d_in[17], d_in[18], d_in[19], d_in[20], d_in[21], flagp, Wf);
  k_lnct<<<dim3(BB*CC), dim3(256), 0, stream>>>(x, flagp, Wf, mu_a, rs_a, xw1c, xw1g, lhsc, rhsc, xw1t);
  k_prep_bn<<<dim3((BB*NN*TT+255)/256), dim3(256), 0, stream>>>(x, flagp, mu_a, rs_a, Wf, xw1g, rhst, rhsg, lhsg);
  k_att_ct<<<dim3(BB, 2), dim3(256), 0, stream>>>(lhsc, rhsc, xw1t, rhst, Wf, Mc, attt);
  if (gemm_path) {
    k_prep_w<<<dim3(16 + (BB*192*128+255)/256), dim3(256), 0, stream>>>(Wf, Mc, Agm, tb_bias, Apre);
    k_attg<<<dim3((NN+63)/64, BB), dim3(256), 0, stream>>>(lhsg, rhsg, adj, attgh);
    k_hgc_mfma<<<dim3((NT+63)/64, BB), dim3(256), 0, stream>>>(x, flagp, mu_a, rs_a, Wf, Apre, hg, resg, out);
    k_tb_mfma<<<dim3((NN+7)/8, BB), dim3(256), 0, stream>>>(x, flagp, mu_a, rs_a, Wf, attt, Agm, tb_bias, out);
    k_gemm_g<<<dim3(GO/64, (NN+63)/64, BB), dim3(256), 0, stream>>>(attgh, hg, resg, flagp, out);
  } else {
    k_cmix<<<dim3((NT+63)/64, BB), dim3(256), 0, stream>>>(Mc, x, flagp, mu_a, rs_a, Wf, out);
    k_graph<<<dim3(NN, BB), dim3(256), 0, stream>>>(lhsg, rhsg, adj, x, flagp, mu_a, rs_a, Wf, out);
    k_tbranch<<<dim3((NN+3)/4, BB), dim3(256), 0, stream>>>(x, flagp, mu_a, rs_a, Wf, attt, out, 0);
    k_res_final<<<dim3((NT+63)/64, 3, BB), dim3(256), 0, stream>>>(x, flagp, Wf, out);
  }
}

// Round 8
// 678.462 us; speedup vs baseline: 1.0162x; 1.0162x over previous
//
#include <hip/hip_runtime.h>
#include <hip/hip_bf16.h>

#define BB 32
#define CC 64
#define NN 307
#define TT 24
#define CO 192
#define NT (NN*TT)   // 7368
#define GO 1536      // CC*TT

using bf16 = __hip_bfloat16;
typedef __attribute__((ext_vector_type(8))) short bf16x8;
typedef __attribute__((ext_vector_type(4))) float f32x4;

// fp32 weight-arena offsets (element = float)
#define OFF_ln_g   0
#define OFF_ln_b   24
#define OFF_res_W  48
#define OFF_res_b  12336
#define OFF_ca_W1  12528
#define OFF_ca_W2  12552
#define OFF_ca_W3  19920
#define OFF_cc_W   20227
#define OFF_cc_b   24323
#define OFF_ta_W1  24387
#define OFF_ta_W2  24694
#define OFF_ta_W3  44342
#define OFF_tc_W0  44406
#define OFF_tc_b0  52598
#define OFF_tc_W1  52662
#define OFF_tc_b1  60854
#define OFF_ga_W1  60918
#define OFF_ga_W2  60942
#define OFF_ga_W3  62478
#define OFF_g_W    62542
#define W_TOTAL    66638

__device__ __forceinline__ float xload(const void* p, size_t i, int f) {
  return f ? ((const float*)p)[i] : __bfloat162float(((const bf16*)p)[i]);
}
__device__ __forceinline__ void ostore(void* p, size_t i, float v, int f) {
  if (f) ((float*)p)[i] = v; else ((bf16*)p)[i] = __float2bfloat16(v);
}
__device__ __forceinline__ float oload(const void* p, size_t i, int f) {
  return f ? ((const float*)p)[i] : __bfloat162float(((const bf16*)p)[i]);
}

__global__ void MEAM_44787918963464_kernel() {}

// ---- 0b. convert all small weights to fp32 arena (inline dtype probe from p0 = ln_g)
__global__ __launch_bounds__(256) void k_cvt_w(
    const void* p0, const void* p1, const void* p2, const void* p3,
    const void* p4, const void* p5, const void* p6, const void* p7,
    const void* p8, const void* p9, const void* p10, const void* p11,
    const void* p12, const void* p13, const void* p14, const void* p15,
    const void* p16, const void* p17, const void* p18, const void* p19,
    int* flagp, float* dst) {
  int i = blockIdx.x*256 + threadIdx.x;
  unsigned w0 = *(const unsigned*)p0;
  int f = (w0 == 0x3F800000u) ? 1 : 0;
  if (i == 0) *flagp = f;
  if (i >= W_TOTAL) return;
  const void* ps[20] = {p0,p1,p2,p3,p4,p5,p6,p7,p8,p9,p10,p11,p12,p13,p14,p15,p16,p17,p18,p19};
  const int sz[20] = {24,24,12288,192,24,7368,307,4096,64,307,19648,64,8192,64,8192,64,24,1536,64,4096};
  int s = 0, base = 0;
  while (i >= base + sz[s]) { base += sz[s]; s++; }
  dst[i] = f ? ((const float*)ps[s])[i-base]
             : __bfloat162float(((const bf16*)ps[s])[i-base]);
}

// ---- 0c. composed t-branch conv matrices (4 taps) + residual tap + biases
__global__ __launch_bounds__(256) void k_prep_tc(const float* __restrict__ W,
    bf16* __restrict__ Ag, float* __restrict__ tb_bias) {
  int g = blockIdx.x*256 + threadIdx.x;
  if (g >= CC*CC) return;
  int pI = g >> 6, c = g & 63;
  const float* W0 = W + OFF_tc_W0;
  const float* b0 = W + OFF_tc_b0;
  const float* W1 = W + OFF_tc_W1;
  const float* b1 = W + OFF_tc_b1;
  const float* resW = W + OFF_res_W;
  const float* resb = W + OFF_res_b;
  float m0=0.f,m1=0.f,m2=0.f,m3=0.f, bb0=0.f, bb2=0.f;
  for (int o=0;o<CC;o++){
    float a1v = W1[(pI*CC+o)*2], b1v = W1[(pI*CC+o)*2+1];
    float a0v = W0[(o*CC+c)*2],  b0v = W0[(o*CC+c)*2+1];
    m0 += b1v*b0v; m1 += b1v*a0v; m2 += a1v*b0v; m3 += a1v*a0v;
    bb0 += b1v*b0[o]; bb2 += a1v*b0[o];
  }
  Ag[pI*320 + 0*64 + c] = __float2bfloat16(m0);
  Ag[pI*320 + 1*64 + c] = __float2bfloat16(m1);
  Ag[pI*320 + 2*64 + c] = __float2bfloat16(m2);
  Ag[pI*320 + 3*64 + c] = __float2bfloat16(m3);
  Ag[pI*320 + 4*64 + c] = __float2bfloat16(resW[(64+pI)*CC + c]);
  if (c == 0){
    tb_bias[pI]    = b1[pI] + bb0 + resb[64+pI];
    tb_bias[64+pI] = bb2;
  }
}

// ---- 0d. Apre[b][192][128] bf16 = [[Mc|resW0..63],[gW|0],[0|resW128..191]]
__global__ __launch_bounds__(256) void k_prep_A(const float* __restrict__ Mc,
    const float* __restrict__ W, bf16* __restrict__ Apre) {
  int idx = blockIdx.x*256 + threadIdx.x;
  if (idx >= BB*192*128) return;
  int b = idx / 24576;
  int rem = idx - b*24576;
  int p2 = rem >> 7, k = rem & 127;
  const float* resW = W + OFF_res_W;
  const float* gW   = W + OFF_g_W;
  float v;
  if (p2 < 64)       v = (k < 64) ? Mc[b*CC*CC + p2*CC + k] : resW[p2*CC + (k-64)];
  else if (p2 < 128) v = (k < 64) ? gW[(p2-64)*CC + k] : 0.f;
  else               v = (k < 64) ? 0.f : resW[p2*CC + (k-64)];
  Apre[idx] = __float2bfloat16(v);
}

// ---- 1. FUSED LN + per-(b,c,t) reductions. One block per (b,c).
__global__ __launch_bounds__(256) void k_lnct(const void* __restrict__ x, const int* flagp,
    const float* __restrict__ W,
    float* __restrict__ mu_a, float* __restrict__ rs_a,
    float* __restrict__ xw1c, float* __restrict__ xw1g,
    float* __restrict__ lhsc, float* __restrict__ rhsc, float* __restrict__ xw1t) {
  int bc = blockIdx.x;            // (b*CC + c)
  int tid = threadIdx.x;
  int f = *flagp;
  const float* lng  = W + OFF_ln_g;
  const float* lnb  = W + OFF_ln_b;
  const float* caW1 = W + OFF_ca_W1;
  const float* gaW1 = W + OFF_ga_W1;
  const float* caW2 = W + OFF_ca_W2;
  const float* caW3 = W + OFF_ca_W3;
  const float* taW1 = W + OFF_ta_W1;
  __shared__ float xs[NN*25];     // 30.7KB, row-padded
  __shared__ float mus[NN], rss[NN], w1c[NN];
  __shared__ float red[3*240];
  size_t base = (size_t)bc * NT;
  if (f) {
    const float4* xp = (const float4*)((const float*)x + base);
    for (int e=tid; e<NT/4; e+=256){
      float4 q = xp[e];
      int n = e/6; int t0 = e*4 - n*24;
      float* d = &xs[n*25 + t0];
      d[0]=q.x; d[1]=q.y; d[2]=q.z; d[3]=q.w;
    }
  } else {
    const uint4* xp = (const uint4*)((const unsigned short*)x + base);
    for (int e=tid; e<NT/8; e+=256){
      uint4 q = xp[e]; unsigned u[4]={q.x,q.y,q.z,q.w};
      int n = e/3; int t0 = e*8 - n*24;
      float* d = &xs[n*25 + t0];
      #pragma unroll
      for (int k=0;k<4;k++){
        union{unsigned uu;float fl;} lo,hi;
        lo.uu=u[k]<<16; hi.uu=u[k]&0xffff0000u;
        d[k*2]=lo.fl; d[k*2+1]=hi.fl;
      }
    }
  }
  __syncthreads();
  for (int n=tid; n<NN; n+=256){
    const float* row = &xs[n*25];
    float mu=0.f;
    #pragma unroll
    for (int t=0;t<TT;t++) mu += row[t];
    mu *= (1.f/TT);
    float var=0.f;
    #pragma unroll
    for (int t=0;t<TT;t++){ float d=row[t]-mu; var += d*d; }
    var *= (1.f/TT);
    float rs = rsqrtf(var+1e-5f);
    float s1=0.f, s2=0.f;
    #pragma unroll
    for (int t=0;t<TT;t++){
      float hv=(row[t]-mu)*rs*lng[t]+lnb[t];
      s1+=hv*caW1[t]; s2+=hv*gaW1[t];
    }
    mus[n]=mu; rss[n]=rs; w1c[n]=s1;
    int gi = bc*NN+n;
    mu_a[gi]=mu; rs_a[gi]=rs; xw1c[gi]=s1; xw1g[gi]=s2;
  }
  __syncthreads();
  int t = tid % TT, g = tid / TT;   // 10 full n-groups (g<10)
  if (g < 10){
    float gt=lng[t], bt=lnb[t];
    float l=0.f, rr=0.f, xt=0.f;
    for (int n=g; n<NN; n+=10){
      float hv=(xs[n*25+t]-mus[n])*rss[n]*gt+bt;
      l += w1c[n]*caW2[n*TT+t];
      rr+= caW3[n]*hv;
      xt+= taW1[n]*hv;
    }
    red[g*TT+t]=l; red[240+g*TT+t]=rr; red[480+g*TT+t]=xt;
  }
  __syncthreads();
  if (tid < TT){
    float L=0.f,R=0.f,X=0.f;
    #pragma unroll
    for (int g2=0; g2<10; g2++){
      L+=red[g2*TT+tid]; R+=red[240+g2*TT+tid]; X+=red[480+g2*TT+tid];
    }
    lhsc[bc*TT+tid]=L; rhsc[bc*TT+tid]=R; xw1t[bc*TT+tid]=X;
  }
}

// ---- 3. per (b,n,t): rhs_t, rhs_g, lhs_g (reduce over c) — LDS-staged, coalesced.
//   Block = (8-n chunk, b). Stage x[64c][8n][24t] (768B contiguous per c) + mu/rs.
__global__ __launch_bounds__(256) void k_prep_bn(const void* __restrict__ x, const int* flagp,
    const float* __restrict__ mu_a, const float* __restrict__ rs_a,
    const float* __restrict__ W, const float* __restrict__ xw1g,
    float* __restrict__ rhst, float* __restrict__ rhsg, float* __restrict__ lhsg) {
  int nc = blockIdx.x, b = blockIdx.y, tid = threadIdx.x;
  int n0 = nc*8;
  int f = *flagp;
  const float* lng  = W + OFF_ln_g;
  const float* lnb  = W + OFF_ln_b;
  const float* taW3 = W + OFF_ta_W3;
  const float* gaW3 = W + OFF_ga_W3;
  const float* gaW2 = W + OFF_ga_W2;
  __shared__ float xs[CC*192];        // 48KB: [c][i*24+t]
  __shared__ float mu_s[CC*8], rs_s[CC*8], w1g_s[CC*8];
  bool full = (n0 + 8 <= NN);
  if (full) {
    if (f) {
      for (int e=tid; e<CC*48; e+=256){    // float4s
        int c = e/48, r4 = e - (e/48)*48;
        float4 q = ((const float4*)((const float*)x + (size_t)(b*CC+c)*NT + n0*TT))[r4];
        float* d = &xs[c*192 + r4*4];
        d[0]=q.x; d[1]=q.y; d[2]=q.z; d[3]=q.w;
      }
    } else {
      for (int e=tid; e<CC*24; e+=256){    // uint4s (8 bf16)
        int c = e/24, r8 = e - (e/24)*24;
        uint4 q = ((const uint4*)((const unsigned short*)x + (size_t)(b*CC+c)*NT + n0*TT))[r8];
        unsigned u[4]={q.x,q.y,q.z,q.w};
        float* d = &xs[c*192 + r8*8];
        #pragma unroll
        for (int k=0;k<4;k++){
          union{unsigned uu;float fl;} lo,hi;
          lo.uu=u[k]<<16; hi.uu=u[k]&0xffff0000u;
          d[k*2]=lo.fl; d[k*2+1]=hi.fl;
        }
      }
    }
  } else {
    for (int e=tid; e<CC*192; e+=256){
      int c = e/192, r = e - (e/192)*192;
      int n = n0 + r/24;
      xs[e] = (n<NN) ? xload(x, (size_t)(b*CC+c)*NT + n0*TT + r, f) : 0.f;
    }
  }
  for (int e=tid; e<CC*8; e+=256){
    int c = e>>3, i = e&7; int n = n0+i;
    if (n < NN){
      int r = (b*CC+c)*NN + n;
      mu_s[e]=mu_a[r]; rs_s[e]=rs_a[r]; w1g_s[e]=xw1g[r];
    } else { mu_s[e]=0.f; rs_s[e]=0.f; w1g_s[e]=0.f; }
  }
  __syncthreads();
  if (tid < 192){
    int i = tid/24, t = tid - (tid/24)*24;
    int n = n0 + i;
    if (n < NN){
      float gt = lng[t], bt = lnb[t];
      float a=0.f, c2=0.f, d=0.f;
      for (int c=0;c<CC;c++){
        float hv = (xs[c*192 + tid] - mu_s[c*8+i]) * rs_s[c*8+i] * gt + bt;
        a  += taW3[c]*hv;
        c2 += gaW3[c]*hv;
        d  += w1g_s[c*8+i]*gaW2[c*TT+t];
      }
      int o = (b*NN+n)*TT + t;
      rhst[o]=a; rhsg[o]=c2; lhsg[o]=d;
    }
  }
}

// ---- 4. lhs_t[b,t,n] = sum_c xW1_t[b,c,t]*taW2[c,n]
__global__ __launch_bounds__(256) void k_lhs_t(const float* __restrict__ xw1t,
    const float* __restrict__ W, float* __restrict__ lhst) {
  int i = blockIdx.x*256 + threadIdx.x;     // (b*T+t)*N + n
  if (i >= BB*TT*NN) return;
  const float* taW2 = W + OFF_ta_W2;
  int n = i % NN; int t = (i/NN)%TT; int b = i/(TT*NN);
  float acc=0.f;
  for (int c=0;c<CC;c++)
    acc += xw1t[(b*CC+c)*TT+t]*taW2[c*NN+n];
  lhst[i]=acc;
}

// ---- 5. channel attention softmax folded with cc_W -> Mc[o][d]
__global__ __launch_bounds__(256) void k_att_c(const float* __restrict__ lhsc,
    const float* __restrict__ rhsc, const float* __restrict__ W,
    float* __restrict__ Mc) {
  int b = blockIdx.x; int tid = threadIdx.x;
  const float* ccW = W + OFF_cc_W;
  __shared__ float lc[CC*TT], rc[CC*TT], sc[CC*(CC+1)];
  for (int e=tid;e<CC*TT;e+=256){
    lc[e]=lhsc[b*CC*TT+e];
    rc[e]=rhsc[b*CC*TT+e];
  }
  __syncthreads();
  for (int e=tid;e<CC*CC;e+=256){
    int c=e>>6, d=e&63; float s=0.f;
    for (int t=0;t<TT;t++) s += lc[c*TT+t]*rc[d*TT+t];
    sc[c*(CC+1)+d]=s;
  }
  __syncthreads();
  if (tid<CC){
    float mx=-1e30f;
    for (int d=0;d<CC;d++) mx=fmaxf(mx, sc[tid*(CC+1)+d]);
    float sum=0.f;
    for (int d=0;d<CC;d++){ float e2=__expf(sc[tid*(CC+1)+d]-mx); sc[tid*(CC+1)+d]=e2; sum+=e2; }
    float inv=1.f/sum;
    for (int d=0;d<CC;d++) sc[tid*(CC+1)+d]*=inv;
  }
  __syncthreads();
  for (int e=tid;e<CC*CC;e+=256){
    int o=e>>6, d=e&63; float acc=0.f;
    for (int c=0;c<CC;c++) acc += ccW[o*CC+c]*sc[c*(CC+1)+d];
    Mc[b*CC*CC+e]=acc;
  }
}

// ---- 6. temporal attention 24x24 softmax
__global__ __launch_bounds__(256) void k_att_t(const float* __restrict__ lhst,
    const float* __restrict__ rhst, float* __restrict__ attt) {
  int b=blockIdx.x, tid=threadIdx.x;
  __shared__ float sc[TT*TT];
  for (int e=tid;e<TT*TT;e+=256){
    int t=e/TT, s=e%TT;
    float acc=0.f;
    for (int n=0;n<NN;n++)
      acc += lhst[(b*TT+t)*NN+n]*rhst[(b*NN+n)*TT+s];
    sc[e]=acc;
  }
  __syncthreads();
  if (tid < TT){
    float mx=-1e30f;
    for (int s=0;s<TT;s++) mx=fmaxf(mx,sc[tid*TT+s]);
    float sum=0.f;
    for (int s=0;s<TT;s++){ float e=__expf(sc[tid*TT+s]-mx); sc[tid*TT+s]=e; sum+=e; }
    float inv=1.f/sum;
    for (int s=0;s<TT;s++) attt[b*TT*TT + tid*TT + s]=sc[tid*TT+s]*inv;
  }
}

// ---- 7a1. graph attention scores via MFMA (hi/lo bf16 split for ~fp32 accuracy)
__global__ __launch_bounds__(256) void k_scores_g(const float* __restrict__ lhsg,
    const float* __restrict__ rhsg, const int* __restrict__ adj,
    float* __restrict__ Sg) {
  int mt = blockIdx.x, nt = blockIdx.y, b = blockIdx.z;
  int n0 = nt*64, m0 = mt*64, tid = threadIdx.x;
  __shared__ unsigned short Lh[64*40], Ll[64*40], Rh[64*40], Rl[64*40];
  for (int e=tid; e<64*24; e+=256){
    int r=e/24, t=e-(e/24)*24;
    int gn=n0+r, gm=m0+r;
    float lv = (gn<NN)? lhsg[((size_t)b*NN+gn)*TT+t] : 0.f;
    float rv = (gm<NN)? rhsg[((size_t)b*NN+gm)*TT+t] : 0.f;
    bf16 lh=__float2bfloat16(lv); float lhf=__bfloat162float(lh);
    bf16 llo=__float2bfloat16(lv-lhf);
    bf16 rh=__float2bfloat16(rv); float rhf=__bfloat162float(rh);
    bf16 rlo=__float2bfloat16(rv-rhf);
    Lh[r*40+t]=*(unsigned short*)&lh; Ll[r*40+t]=*(unsigned short*)&llo;
    Rh[r*40+t]=*(unsigned short*)&rh; Rl[r*40+t]=*(unsigned short*)&rlo;
  }
  for (int e=tid; e<64*8; e+=256){
    int r=e>>3, t=24+(e&7);
    Lh[r*40+t]=0; Ll[r*40+t]=0; Rh[r*40+t]=0; Rl[r*40+t]=0;
  }
  __syncthreads();
  int lane=tid&63, w=tid>>6, q=lane>>4, lr=lane&15;
  bf16x8 ah = *(const bf16x8*)&Lh[(w*16+lr)*40 + q*8];
  bf16x8 al = *(const bf16x8*)&Ll[(w*16+lr)*40 + q*8];
  f32x4 z4={0.f,0.f,0.f,0.f};
  f32x4 acc[4]={z4,z4,z4,z4};
  #pragma unroll
  for (int ct=0;ct<4;ct++){
    bf16x8 bh = *(const bf16x8*)&Rh[(ct*16+lr)*40 + q*8];
    bf16x8 bl = *(const bf16x8*)&Rl[(ct*16+lr)*40 + q*8];
    acc[ct]=__builtin_amdgcn_mfma_f32_16x16x32_bf16(ah,bh,acc[ct],0,0,0);
    acc[ct]=__builtin_amdgcn_mfma_f32_16x16x32_bf16(ah,bl,acc[ct],0,0,0);
    acc[ct]=__builtin_amdgcn_mfma_f32_16x16x32_bf16(al,bh,acc[ct],0,0,0);
  }
  #pragma unroll
  for (int ct=0;ct<4;ct++){
    int m = m0 + ct*16 + lr;
    #pragma unroll
    for (int r=0;r<4;r++){
      int n = n0 + w*16 + q*4 + r;
      if (n<NN && m<NN){
        float s = acc[ct][r];
        if (adj[n*NN+m] <= 0) s = -1e30f;
        Sg[((size_t)b*NN+n)*NN+m] = s;
      }
    }
  }
}

// ---- 7a2. row softmax of Sg -> attgh bf16. One wave per row, shfl reductions.
__global__ __launch_bounds__(256) void k_smax_g(const float* __restrict__ Sg,
    bf16* __restrict__ attgh) {
  int b = blockIdx.y;
  int n = blockIdx.x*4 + (threadIdx.x>>6);
  int lane = threadIdx.x & 63;
  if (n >= NN) return;
  const float* row = Sg + ((size_t)b*NN+n)*NN;
  float v[5]; float mx = -1e30f;
  #pragma unroll
  for (int i=0;i<5;i++){
    int m = lane + i*64;
    v[i] = (m<NN)? row[m] : -1e30f;
    mx = fmaxf(mx, v[i]);
  }
  #pragma unroll
  for (int off=32; off; off>>=1) mx = fmaxf(mx, __shfl_xor(mx, off));
  float sum = 0.f;
  #pragma unroll
  for (int i=0;i<5;i++){
    int m = lane + i*64;
    float e = (m<NN)? __expf(v[i]-mx) : 0.f;
    v[i]=e; sum += e;
  }
  #pragma unroll
  for (int off=32; off; off>>=1) sum += __shfl_xor(sum, off);
  float inv = 1.f/sum;
  bf16* orow = attgh + ((size_t)b*NN+n)*NN;
  #pragma unroll
  for (int i=0;i<5;i++){
    int m = lane + i*64;
    if (m<NN) orow[m] = __float2bfloat16(v[i]*inv);
  }
}

// ---- 7b. fused c-branch + residual(0..63) + hg + residual(128..191 -> resg bf16) via MFMA.
__global__ __launch_bounds__(256) void k_hgc_mfma(
    const void* __restrict__ x, const int* flagp,
    const float* __restrict__ mu_a, const float* __restrict__ rs_a,
    const float* __restrict__ W, const bf16* __restrict__ Apre,
    bf16* __restrict__ hg, bf16* __restrict__ resg, void* __restrict__ out) {
  int jt = blockIdx.x, b = blockIdx.y, tid = threadIdx.x;
  int f = *flagp;
  int j0 = jt*64;
  const float* lng = W + OFF_ln_g;
  const float* lnb = W + OFF_ln_b;
  const float* ccb = W + OFF_cc_b;
  const float* resb= W + OFF_res_b;
  __shared__ unsigned short Bs[64*128];   // [j][k] bf16, 16KB

  {
    int c = tid >> 2, jg = tid & 3;
    float xv[16];
    int jbase = j0 + jg*16;
    size_t xoff = (size_t)(b*CC + c)*NT + jbase;
    if (jbase + 15 < NT) {
      if (f) {
        const float4* xp = (const float4*)((const float*)x + xoff);
        #pragma unroll
        for (int v=0; v<4; v++){ float4 q = xp[v]; xv[v*4]=q.x; xv[v*4+1]=q.y; xv[v*4+2]=q.z; xv[v*4+3]=q.w; }
      } else {
        const uint4* xp = (const uint4*)((const unsigned short*)x + xoff);
        #pragma unroll
        for (int v=0; v<2; v++){
          uint4 q = xp[v]; unsigned u[4]={q.x,q.y,q.z,q.w};
          #pragma unroll
          for (int kk2=0;kk2<4;kk2++){
            union{unsigned uu;float fl;} lo,hi;
            lo.uu=u[kk2]<<16; hi.uu=u[kk2]&0xffff0000u;
            xv[v*8+kk2*2]=lo.fl; xv[v*8+kk2*2+1]=hi.fl;
          }
        }
      }
    } else {
      #pragma unroll
      for (int i=0;i<16;i++){ int j=jbase+i; xv[i] = (j<NT)? xload(x, xoff+i, f) : 0.f; }
    }
    const float* mu_r = mu_a + (b*CC+c)*NN;
    const float* rs_r = rs_a + (b*CC+c)*NN;
    #pragma unroll
    for (int i=0;i<16;i++){
      int j = jbase + i;
      int jl = jg*16 + i;
      float hv = 0.f, xf = 0.f;
      if (j < NT){
        int n = j / 24, t = j - n*24;
        xf = xv[i];
        hv = (xf - mu_r[n]) * rs_r[n] * lng[t] + lnb[t];
      }
      int cs = c ^ ((jl&7)<<3);
      bf16 hb = __float2bfloat16(hv), xb = __float2bfloat16(xf);
      Bs[jl*128 + cs]      = *(unsigned short*)&hb;
      Bs[jl*128 + cs + 64] = *(unsigned short*)&xb;
    }
  }

  int lane = tid & 63, w = tid >> 6;
  int q = lane >> 4, lr = lane & 15;
  bf16x8 afo[4], afh[2], afr[2];
  {
    const unsigned short* Ab = (const unsigned short*)Apre + (size_t)b*24576;
    const unsigned short* r0 = Ab + (w*16 + lr)*128;
    #pragma unroll
    for (int kc=0;kc<4;kc++) afo[kc] = *(const bf16x8*)&r0[kc*32 + q*8];
    const unsigned short* r1 = Ab + (64 + w*16 + lr)*128;
    #pragma unroll
    for (int kc=0;kc<2;kc++) afh[kc] = *(const bf16x8*)&r1[kc*32 + q*8];
    const unsigned short* r2 = Ab + (128 + w*16 + lr)*128;
    #pragma unroll
    for (int kc=0;kc<2;kc++) afr[kc] = *(const bf16x8*)&r2[(kc+2)*32 + q*8];
  }
  f32x4 z4 = {0.f,0.f,0.f,0.f};
  f32x4 acco[4] = {z4,z4,z4,z4};
  f32x4 acch[4] = {z4,z4,z4,z4};
  f32x4 accr[4] = {z4,z4,z4,z4};
  __syncthreads();

  #pragma unroll
  for (int ct=0; ct<4; ct++){
    int jl = ct*16 + lr;
    int sw = ((jl&7)<<3);
    #pragma unroll
    for (int kc=0; kc<4; kc++){
      int ke = (kc*32 + q*8) ^ sw;
      bf16x8 bfr = *(const bf16x8*)&Bs[jl*128 + ke];
      acco[ct] = __builtin_amdgcn_mfma_f32_16x16x32_bf16(afo[kc], bfr, acco[ct], 0,0,0);
      if (kc < 2)
        acch[ct] = __builtin_amdgcn_mfma_f32_16x16x32_bf16(afh[kc], bfr, acch[ct], 0,0,0);
      else
        accr[ct] = __builtin_amdgcn_mfma_f32_16x16x32_bf16(afr[kc-2], bfr, accr[ct], 0,0,0);
    }
  }

  #pragma unroll
  for (int ct=0;ct<4;ct++){
    int jl = ct*16 + lr;
    int j = j0 + jl;
    if (j < NT){
      #pragma unroll
      for (int r=0;r<4;r++){
        int p2 = w*16 + q*4 + r;
        float v = acco[ct][r] + ccb[p2] + resb[p2];
        ostore(out, ((size_t)b*CO + p2)*NT + j, fmaxf(v,0.f), f);
      }
      int n = j/24, t2 = j - n*24;
      size_t hb2 = ((size_t)b*NN + n)*GO + t2;
      #pragma unroll
      for (int r=0;r<4;r++){
        int o = w*16 + q*4 + r;
        hg[hb2 + o*TT] = __float2bfloat16(acch[ct][r]);
      }
      #pragma unroll
      for (int r=0;r<4;r++){
        int p3 = w*16 + q*4 + r;
        resg[((size_t)b*CC + p3)*NT + j] = __float2bfloat16(accr[ct][r] + resb[128+p3]);
      }
    }
  }
}

// ---- 7c. graph GEMM, MFMA bf16: out[128+o] = relu(attg@hg + resg)
__global__ __launch_bounds__(256) void k_gemm_g(const bf16* __restrict__ attgh,
    const bf16* __restrict__ hg, const bf16* __restrict__ resg,
    const int* flagp, void* __restrict__ out) {
  int jt = blockIdx.x, nt = blockIdx.y, b = blockIdx.z;
  int tid = threadIdx.x;
  int f = *flagp;
  int n0 = nt*64, j0 = jt*64;
  __shared__ unsigned short As[64*72];
  __shared__ unsigned short Bs[64*72];
  int lane = tid & 63, w = tid >> 6;
  int q = lane >> 4, lr = lane & 15;
  f32x4 z4 = {0.f,0.f,0.f,0.f};
  f32x4 acc[4] = {z4,z4,z4,z4};
  const unsigned short* Ag = (const unsigned short*)attgh + (size_t)b*NN*NN;
  const unsigned short* Bg = (const unsigned short*)hg + (size_t)b*NN*GO;
  for (int m0=0;m0<NN;m0+=64){
    for (int u=tid; u<512; u+=256){
      int r=u>>3, kb=(u&7)*8;
      int gn=n0+r, gm=m0+kb;
      if (gn<NN && gm+7<NN){
        *(uint4*)&As[r*72+kb] = *(const uint4*)&Ag[(size_t)gn*NN + gm];
      } else {
        for (int i2=0;i2<8;i2++){
          int m=gm+i2;
          As[r*72+kb+i2] = (gn<NN && m<NN) ? Ag[(size_t)gn*NN+m] : 0;
        }
      }
    }
    for (int u=tid; u<512; u+=256){
      int m = u>>3, jb = (u&7)*8;       // coalesced: 8 lanes read 128B of row gm
      int gm = m0 + m;
      unsigned short s[8];
      if (gm < NN){
        *(uint4*)s = *(const uint4*)&Bg[(size_t)gm*GO + j0 + jb];
      } else {
        #pragma unroll
        for (int i2=0;i2<8;i2++) s[i2]=0;
      }
      int mb = m>>3, ml2 = m&7;
      #pragma unroll
      for (int i2=0;i2<8;i2++){
        int j = jb + i2;
        int col = ((mb ^ (j>>3)) << 3) | ml2;
        Bs[j*72 + col] = s[i2];
      }
    }
    __syncthreads();
    #pragma unroll
    for (int kk=0;kk<64;kk+=32){
      bf16x8 af = *(const bf16x8*)&As[(w*16+lr)*72 + kk + q*8];
      #pragma unroll
      for (int ct=0;ct<4;ct++){
        int jrow = ct*16+lr;
        int kb = kk + q*8;
        int col = (((kb>>3) ^ (jrow>>3)) << 3);
        bf16x8 bfr = *(const bf16x8*)&Bs[jrow*72 + col];
        acc[ct] = __builtin_amdgcn_mfma_f32_16x16x32_bf16(af, bfr, acc[ct], 0,0,0);
      }
    }
    __syncthreads();
  }
  #pragma unroll
  for (int ct=0;ct<4;ct++){
    #pragma unroll
    for (int r=0;r<4;r++){
      int n = n0 + w*16 + q*4 + r;
      if (n >= NN) continue;
      int j = j0 + ct*16 + lr;
      int o = j/TT, t2 = j%TT;
      size_t idx = ((size_t)b*CO + 128 + o)*NT + (size_t)n*TT + t2;
      float v = acc[ct][r] + __bfloat162float(resg[((size_t)b*CC + o)*NT + (size_t)n*TT + t2]);
      ostore(out, idx, fmaxf(v, 0.f), f);
    }
  }
}

// ---- 8f. FALLBACK c-branch (raw write)
__global__ __launch_bounds__(256) void k_cmix(const float* __restrict__ Mc,
    const void* __restrict__ x, const int* flagp,
    const float* __restrict__ mu_a, const float* __restrict__ rs_a,
    const float* __restrict__ W, void* __restrict__ out) {
  int jt=blockIdx.x, b=blockIdx.y, tid=threadIdx.x;
  int f = *flagp;
  int j0=jt*64;
  const float* lng = W + OFF_ln_g;
  const float* lnb = W + OFF_ln_b;
  const float* ccb = W + OFF_cc_b;
  __shared__ float Ms[CC*64];
  __shared__ float Hs[CC*64];
  for (int e=tid;e<CC*64;e+=256){
    int o=e&63, d=e>>6;
    Ms[e]=Mc[b*CC*CC + o*CC + d];
  }
  for (int e=tid;e<CC*64;e+=256){
    int d=e>>6, j=e&63; int jj=j0+j;
    float hv = 0.f;
    if (jj<NT){
      int n = jj/TT, t = jj%TT;
      int row = (b*CC+d)*NN + n;
      hv = (xload(x, (size_t)(b*CC+d)*NT + jj, f) - mu_a[row]) * rs_a[row] * lng[t] + lnb[t];
    }
    Hs[e]=hv;
  }
  __syncthreads();
  int ti=tid&15, tj=tid>>4;
  float acc[4][4]={};
  for (int d=0;d<CC;d++){
    float4 a4=*(const float4*)&Ms[d*64+ti*4];
    float4 b4=*(const float4*)&Hs[d*64+tj*4];
    float av[4]={a4.x,a4.y,a4.z,a4.w};
    float bv[4]={b4.x,b4.y,b4.z,b4.w};
    for (int i=0;i<4;i++)
      for (int j=0;j<4;j++) acc[i][j]+=av[i]*bv[j];
  }
  for (int i=0;i<4;i++){
    int o=ti*4+i; float bias=ccb[o];
    for (int j=0;j<4;j++){
      int jj=j0+tj*4+j;
      if (jj<NT)
        ostore(out, ((size_t)b*CO+o)*NT+jj, acc[i][j]+bias, f);
    }
  }
}

// ---- 8g. FALLBACK fused g-branch
__global__ __launch_bounds__(256) void k_graph(const float* __restrict__ lhsg,
    const float* __restrict__ rhsg, const int* __restrict__ adj,
    const void* __restrict__ x, const int* flagp,
    const float* __restrict__ mu_a, const float* __restrict__ rs_a,
    const float* __restrict__ W, void* __restrict__ out) {
  int n = blockIdx.x, b = blockIdx.y, tid = threadIdx.x;
  int f = *flagp;
  const float* lng = W + OFF_ln_g;
  const float* lnb = W + OFF_ln_b;
  const float* gW  = W + OFF_g_W;
  __shared__ float ls[TT];
  __shared__ float sv[NN];
  __shared__ float red[256];
  __shared__ float wl[NN];
  __shared__ int   ml[NN];
  __shared__ int   cnt;
  __shared__ float z[CC*TT];
  __shared__ float Gs[CC*CC];
  __shared__ float gs[TT], bs[TT];
  if (tid < TT){
    ls[tid] = lhsg[(b*NN+n)*TT + tid];
    gs[tid] = lng[tid]; bs[tid] = lnb[tid];
  }
  for (int e=tid;e<CC*CC;e+=256) Gs[e]=gW[e];
  __syncthreads();
  float lmax = -1e30f;
  for (int m=tid;m<NN;m+=256){
    float s = -1e30f;
    if (adj[n*NN+m] > 0){
      const float* rr = rhsg + ((size_t)b*NN+m)*TT;
      float acc=0.f;
      for (int t=0;t<TT;t++) acc += ls[t]*rr[t];
      s = acc;
    }
    sv[m]=s; lmax=fmaxf(lmax,s);
  }
  red[tid]=lmax; __syncthreads();
  for (int k=128;k>0;k>>=1){ if (tid<k) red[tid]=fmaxf(red[tid],red[tid+k]); __syncthreads(); }
  float mx = red[0]; __syncthreads();
  float lsum=0.f;
  for (int m=tid;m<NN;m+=256){
    float e = (sv[m] > -1e29f) ? __expf(sv[m]-mx) : 0.f;
    sv[m]=e; lsum+=e;
  }
  red[tid]=lsum; __syncthreads();
  for (int k=128;k>0;k>>=1){ if (tid<k) red[tid]+=red[tid+k]; __syncthreads(); }
  float inv = 1.f/red[0];
  if (tid==0){
    int c=0;
    for (int m=0;m<NN;m++) if (sv[m]!=0.f){ ml[c]=m; wl[c]=sv[m]*inv; c++; }
    cnt=c;
  }
  __syncthreads();
  int K = cnt;
  {
    int c = tid>>2, tg = tid&3;
    float acc[6]={0,0,0,0,0,0};
    float s0 = 0.f;
    const float* mu_r = mu_a + (b*CC+c)*NN;
    const float* rs_r = rs_a + (b*CC+c)*NN;
    size_t xbase = (size_t)(b*CC+c)*NT;
    for (int k=0;k<K;k++){
      int m = ml[k];
      float wr = wl[k]*rs_r[m];
      s0 += wr*mu_r[m];
      size_t xm = xbase + m*TT + tg*6;
      for (int j=0;j<6;j++) acc[j] += wr*xload(x, xm+j, f);
    }
    for (int j=0;j<6;j++){
      int t = tg*6+j;
      z[c*TT+t] = gs[t]*(acc[j]-s0) + bs[t];
    }
  }
  __syncthreads();
  {
    int o = tid>>2, tg = tid&3;
    float acc[6]={0,0,0,0,0,0};
    for (int c=0;c<CC;c++){
      float gwv = Gs[o*CC+c];
      const float* zr = &z[c*TT + tg*6];
      for (int j=0;j<6;j++) acc[j] += gwv*zr[j];
    }
    size_t base = ((size_t)b*CO + 128 + o)*NT + n*TT + tg*6;
    for (int j=0;j<6;j++)
      ostore(out, base+j, acc[j], f);
  }
}

// ---- 9. FALLBACK t-branch
__global__ __launch_bounds__(256) void k_tbranch(const void* __restrict__ x, const int* flagp,
    const float* __restrict__ mu_a, const float* __restrict__ rs_a,
    const float* __restrict__ W, const float* __restrict__ attt,
    void* __restrict__ out, int fuse) {
  int chunk = blockIdx.x, b = blockIdx.y, tid = threadIdx.x;
  int f = *flagp;
  int n0 = chunk*4;
  const float* lng = W + OFF_ln_g;
  const float* lnb = W + OFF_ln_b;
  const float* W0  = W + OFF_tc_W0;
  const float* b0  = W + OFF_tc_b0;
  const float* W1  = W + OFF_tc_W1;
  const float* b1  = W + OFF_tc_b1;
  __shared__ float hs[256*25];
  __shared__ float at[TT*TT];
  for (int e=tid;e<CC*4*TT;e+=256){
    int c=e/(4*TT), rem=e%(4*TT), i=rem/TT, t=rem%TT;
    int n=n0+i;
    float hv=0.f;
    if (n<NN){
      int row=(b*CC+c)*NN+n;
      hv = (xload(x,(size_t)row*TT+t,f) - mu_a[row]) * rs_a[row] * lng[t] + lnb[t];
    }
    hs[(c*4+i)*25+t] = hv;
  }
  for (int e=tid;e<TT*TT;e+=256) at[e]=attt[b*TT*TT+e];
  __syncthreads();
  {
    float r[TT], o2[TT];
    float* myrow = &hs[tid*25];
    #pragma unroll
    for (int s=0;s<TT;s++) r[s]=myrow[s];
    for (int t=0;t<TT;t++){
      float a=0.f;
      #pragma unroll
      for (int s=0;s<TT;s++) a += at[t*TT+s]*r[s];
      o2[t]=a;
    }
    #pragma unroll
    for (int t=0;t<TT;t++) myrow[t]=o2[t];
  }
  __syncthreads();
  {
    int o = tid>>2, i = tid&3;
    float acc[TT];
    float bb = b0[o];
    for (int t=0;t<TT;t++) acc[t]=bb;
    for (int c=0;c<CC;c++){
      float wa = W0[(o*CC+c)*2], wb = W0[(o*CC+c)*2+1];
      const float* row = &hs[(c*4+i)*25];
      acc[0] += wb*row[0];
      #pragma unroll
      for (int t=1;t<TT;t++) acc[t] += wa*row[t-1] + wb*row[t];
    }
    __syncthreads();
    float* myrow = &hs[tid*25];
    #pragma unroll
    for (int t=0;t<TT;t++) myrow[t]=acc[t];
  }
  __syncthreads();
  {
    int o2 = tid>>2, i = tid&3;
    int n = n0+i;
    float acc[TT];
    float bb = b1[o2];
    for (int t=0;t<TT;t++) acc[t]=bb;
    for (int o=0;o<CC;o++){
      float wa = W1[(o2*CC+o)*2], wb = W1[(o2*CC+o)*2+1];
      const float* row = &hs[(o*4+i)*25];
      acc[0] += wb*row[0];
      acc[1] += wb*row[1];
      #pragma unroll
      for (int t=2;t<TT;t++) acc[t] += wa*row[t-2] + wb*row[t];
    }
    if (n<NN){
      size_t base = (((size_t)b*CO + 64 + o2)*NN + n)*TT;
      if (fuse){
        for (int t=0;t<TT;t++){
          float v = acc[t] + oload(out, base+t, f);
          ostore(out, base+t, fmaxf(v,0.f), f);
        }
      } else {
        for (int t=0;t<TT;t++) ostore(out, base+t, acc[t], f);
      }
    }
  }
}

// ---- 9m. t-branch via MFMA: composed 4-tap conv GEMM + fused residual tap, final write.
__device__ __forceinline__ void tb_load_raw(const void* __restrict__ x, int f, int b, int c, int nn,
    float* h) {
  if (nn < NN) {
    size_t off = (size_t)(b*CC + c)*NT + (size_t)nn*TT;
    if (f) {
      const float4* xp = (const float4*)((const float*)x + off);
      #pragma unroll
      for (int v=0; v<6; v++){
        float4 q = xp[v];
        h[v*4+0]=q.x; h[v*4+1]=q.y; h[v*4+2]=q.z; h[v*4+3]=q.w;
      }
    } else {
      const uint4* xp = (const uint4*)((const unsigned short*)x + off);
      #pragma unroll
      for (int v=0; v<3; v++){
        uint4 q = xp[v];
        unsigned wsv[4] = {q.x,q.y,q.z,q.w};
        #pragma unroll
        for (int k=0;k<4;k++){
          union { unsigned u; float fl; } lo, hi;
          lo.u = wsv[k] << 16; hi.u = wsv[k] & 0xffff0000u;
          h[v*8 + k*2] = lo.fl; h[v*8 + k*2 + 1] = hi.fl;
        }
      }
    }
  } else {
    #pragma unroll
    for (int t=0;t<TT;t++) h[t]=0.f;
  }
}

__global__ __launch_bounds__(256) void k_tb_mfma(
    const void* __restrict__ x, const int* flagp,
    const float* __restrict__ mu_a, const float* __restrict__ rs_a,
    const float* __restrict__ W, const float* __restrict__ attt,
    const bf16* __restrict__ Agm, const float* __restrict__ tb_bias,
    void* __restrict__ out) {
  int chunk = blockIdx.x, b = blockIdx.y, tid = threadIdx.x;
  int f = *flagp;
  int n0 = chunk*8;
  const float* lng = W + OFF_ln_g;
  const float* lnb = W + OFF_ln_b;
  __shared__ unsigned short Bs[8*27*64];   // h' [n][s][c], s=t+3, 27648B
  __shared__ unsigned short Xs[8*24*64];   // raw x [n][t][c], 24576B

  for (int e=tid; e<8*3*64; e+=256){
    int n = e/192, rem = e%192, s = rem>>6, cz = rem&63;
    Bs[((n*27+s)<<6) + cz] = 0;
  }

  int c  = tid & 63;
  int nA = tid >> 6;
  float h0[TT], h1[TT];
  tb_load_raw(x, f, b, c, n0+nA,   h0);
  tb_load_raw(x, f, b, c, n0+nA+4, h1);
  #pragma unroll
  for (int t=0;t<TT;t++){
    int cs = c ^ ((t&7)<<3);
    bf16 v0 = __float2bfloat16(h0[t]);
    bf16 v1 = __float2bfloat16(h1[t]);
    Xs[(nA*24+t)*64 + cs]     = *reinterpret_cast<unsigned short*>(&v0);
    Xs[((nA+4)*24+t)*64 + cs] = *reinterpret_cast<unsigned short*>(&v1);
  }
  {
    int nn0 = n0+nA, nn1 = n0+nA+4;
    if (nn0 < NN){
      int r = (b*CC+c)*NN + nn0; float mu = mu_a[r], rs = rs_a[r];
      #pragma unroll
      for (int t=0;t<TT;t++) h0[t] = (h0[t]-mu)*rs*lng[t] + lnb[t];
    }
    if (nn1 < NN){
      int r = (b*CC+c)*NN + nn1; float mu = mu_a[r], rs = rs_a[r];
      #pragma unroll
      for (int t=0;t<TT;t++) h1[t] = (h1[t]-mu)*rs*lng[t] + lnb[t];
    }
  }
  const float* att_b = attt + b*TT*TT;
  for (int t=0;t<TT;t++){
    float a0=0.f, a1=0.f;
    #pragma unroll
    for (int s=0;s<TT;s++){
      float wv = att_b[t*TT+s];
      a0 += wv*h0[s]; a1 += wv*h1[s];
    }
    int sI = t+3;
    int cs = c ^ ((sI&7)<<3);
    bf16 v0 = __float2bfloat16(a0);
    bf16 v1 = __float2bfloat16(a1);
    Bs[((nA*27+sI)<<6) + cs]     = *reinterpret_cast<unsigned short*>(&v0);
    Bs[(((nA+4)*27+sI)<<6) + cs] = *reinterpret_cast<unsigned short*>(&v1);
  }

  int lane = tid & 63, w = tid >> 6;
  int q = lane >> 4, lr = lane & 15;
  bf16x8 af[10];
  const unsigned short* Arow = (const unsigned short*)Agm + (size_t)(w*16+lr)*320;
  #pragma unroll
  for (int kc=0;kc<10;kc++)
    af[kc] = *(const bf16x8*)&Arow[kc*32 + q*8];

  f32x4 z4 = {0.f,0.f,0.f,0.f};
  f32x4 acc[12] = {z4,z4,z4,z4,z4,z4,z4,z4,z4,z4,z4,z4};
  __syncthreads();

  #pragma unroll
  for (int ct=0; ct<12; ct++){
    int col = ct*16 + lr;
    int nl = col/24, t = col - nl*24;
    #pragma unroll
    for (int kc=0;kc<8;kc++){
      int tap = kc>>1;
      int s = t + 3 - tap;
      int cb = ((kc&1)*32 + q*8) ^ ((s&7)<<3);
      bf16x8 bfr = *(const bf16x8*)&Bs[((nl*27+s)<<6) + cb];
      acc[ct] = __builtin_amdgcn_mfma_f32_16x16x32_bf16(af[kc], bfr, acc[ct], 0,0,0);
    }
    #pragma unroll
    for (int kc2=0;kc2<2;kc2++){
      int cb = (kc2*32 + q*8) ^ ((t&7)<<3);
      bf16x8 bfr = *(const bf16x8*)&Xs[(nl*24+t)*64 + cb];
      acc[ct] = __builtin_amdgcn_mfma_f32_16x16x32_bf16(af[8+kc2], bfr, acc[ct], 0,0,0);
    }
  }

  #pragma unroll
  for (int ct=0;ct<12;ct++){
    int col = ct*16 + lr;
    int nl = col/24, t = col - nl*24;
    int nn = n0 + nl;
    if (nn < NN){
      #pragma unroll
      for (int r=0;r<4;r++){
        int pI = w*16 + q*4 + r;
        size_t idx = ((size_t)b*CO + 64 + pI)*NT + (size_t)nn*TT + t;
        float v = acc[ct][r] + tb_bias[pI] + (t>=2 ? tb_bias[64+pI] : 0.f);
        ostore(out, idx, fmaxf(v, 0.f), f);
      }
    }
  }
}

// ---- 10. FALLBACK final: out = relu(out + res_W@x + res_b)
__global__ __launch_bounds__(256) void k_res_final(const void* __restrict__ x, const int* flagp,
    const float* __restrict__ W, void* __restrict__ out) {
  int jt=blockIdx.x, ot=blockIdx.y, b=blockIdx.z; int tid=threadIdx.x;
  int f = *flagp;
  int j0=jt*64, o0=ot*64;
  const float* resW = W + OFF_res_W;
  const float* resb = W + OFF_res_b;
  __shared__ float Ws[CC*64];
  __shared__ float Xs[CC*64];
  for (int e=tid;e<CC*64;e+=256){
    int o=e&63, c=e>>6;
    Ws[e] = resW[(o0+o)*CC + c];
  }
  for (int e=tid;e<CC*64;e+=256){
    int c=e>>6, j=e&63; int jj=j0+j;
    Xs[e] = (jj<NT) ? xload(x, (size_t)(b*CC+c)*NT + jj, f) : 0.f;
  }
  __syncthreads();
  int ti=tid&15, tj=tid>>4;
  float acc[4][4]={};
  for (int k=0;k<CC;k++){
    float4 a4=*(const float4*)&Ws[k*64+ti*4];
    float4 b4=*(const float4*)&Xs[k*64+tj*4];
    float av[4]={a4.x,a4.y,a4.z,a4.w};
    float bv[4]={b4.x,b4.y,b4.z,b4.w};
    for (int i=0;i<4;i++)
      for (int j=0;j<4;j++) acc[i][j]+=av[i]*bv[j];
  }
  for (int i=0;i<4;i++){
    int o=o0+ti*4+i; float bias=resb[o];
    for (int j=0;j<4;j++){
      int jj=j0+tj*4+j;
      if (jj<NT){
        size_t idx=((size_t)b*CO+o)*NT+jj;
        float v = acc[i][j] + bias + oload(out, idx, f);
        ostore(out, idx, fmaxf(v,0.f), f);
      }
    }
  }
}

extern "C" void kernel_launch(void* const* d_in, const int* in_sizes, int n_in,
                              void* d_out, int out_size, void* d_ws, size_t ws_size,
                              hipStream_t stream) {
  const void* x     = d_in[0];
  const int*  adj   = (const int*)d_in[1];
  void* out = d_out;

  float* p = (float*)d_ws;
  int*   flagp = (int*)p; p += 4;
  float* Wf  = p; p += W_TOTAL;
  float* mu_a = p; p += (size_t)BB*CC*NN;
  float* rs_a = p; p += (size_t)BB*CC*NN;
  float* xw1c = p; p += (size_t)BB*CC*NN;
  float* xw1g = p; p += (size_t)BB*CC*NN;
  float* xw1t = p; p += (size_t)BB*CC*TT;
  float* lhsc = p; p += (size_t)BB*CC*TT;
  float* rhsc = p; p += (size_t)BB*CC*TT;
  float* rhst = p; p += (size_t)BB*NN*TT;
  float* rhsg = p; p += (size_t)BB*NN*TT;
  float* lhsg = p; p += (size_t)BB*NN*TT;
  float* lhst = p; p += (size_t)BB*TT*NN;
  float* attt = p; p += (size_t)BB*TT*TT;
  float* Mc   = p; p += (size_t)BB*CC*CC;
  bf16*  Agm  = (bf16*)p; p += 10240;    // 64*320 bf16 composed conv+res matrices
  float* tb_bias = p; p += 128;          // bias0[64], bias2[64]
  bf16*  Apre = (bf16*)p; p += (size_t)BB*192*128/2;   // [b][192][128] bf16
  float* Sg   = p; p += (size_t)BB*NN*NN + 16;         // masked scores fp32
  bf16*  attgh = (bf16*)p; p += (size_t)BB*NN*NN/2 + 16;
  bf16*  resg = (bf16*)p; p += (size_t)BB*CC*NT/2 + 16; // rows 128..191 residual bf16
  bf16*  hg   = (bf16*)p;
  size_t need = ((char*)(hg + (size_t)BB*NN*GO)) - (char*)d_ws;
  bool gemm_path = (ws_size >= need);

  k_cvt_w<<<dim3((W_TOTAL+255)/256), dim3(256), 0, stream>>>(
      d_in[2], d_in[3], d_in[4], d_in[5], d_in[6], d_in[7], d_in[8], d_in[9],
      d_in[10], d_in[11], d_in[12], d_in[13], d_in[14], d_in[15], d_in[16],
      d_in[17], d_in[18], d_in[19], d_in[20], d_in[21], flagp, Wf);
  k_lnct<<<dim3(BB*CC), dim3(256), 0, stream>>>(x, flagp, Wf, mu_a, rs_a, xw1c, xw1g, lhsc, rhsc, xw1t);
  k_prep_bn<<<dim3((NN+7)/8, BB), dim3(256), 0, stream>>>(x, flagp, mu_a, rs_a, Wf, xw1g, rhst, rhsg, lhsg);
  k_lhs_t<<<dim3((BB*TT*NN+255)/256), dim3(256), 0, stream>>>(xw1t, Wf, lhst);
  k_att_c<<<dim3(BB), dim3(256), 0, stream>>>(lhsc, rhsc, Wf, Mc);
  k_att_t<<<dim3(BB), dim3(256), 0, stream>>>(lhst, rhst, attt);
  if (gemm_path) {
    k_prep_tc<<<dim3(16), dim3(256), 0, stream>>>(Wf, Agm, tb_bias);
    k_prep_A<<<dim3((BB*192*128+255)/256), dim3(256), 0, stream>>>(Mc, Wf, Apre);
    int ntile = (NN+63)/64;
    k_scores_g<<<dim3(ntile, ntile, BB), dim3(256), 0, stream>>>(lhsg, rhsg, adj, Sg);
    k_smax_g<<<dim3((NN+3)/4, BB), dim3(256), 0, stream>>>(Sg, attgh);
    k_hgc_mfma<<<dim3((NT+63)/64, BB), dim3(256), 0, stream>>>(x, flagp, mu_a, rs_a, Wf, Apre, hg, resg, out);
    k_tb_mfma<<<dim3((NN+7)/8, BB), dim3(256), 0, stream>>>(x, flagp, mu_a, rs_a, Wf, attt, Agm, tb_bias, out);
    k_gemm_g<<<dim3(GO/64, (NN+63)/64, BB), dim3(256), 0, stream>>>(attgh, hg, resg, flagp, out);
  } else {
    k_cmix<<<dim3((NT+63)/64, BB), dim3(256), 0, stream>>>(Mc, x, flagp, mu_a, rs_a, Wf, out);
    k_graph<<<dim3(NN, BB), dim3(256), 0, stream>>>(lhsg, rhsg, adj, x, flagp, mu_a, rs_a, Wf, out);
    k_tbranch<<<dim3((NN+3)/4, BB), dim3(256), 0, stream>>>(x, flagp, mu_a, rs_a, Wf, attt, out, 0);
    k_res_final<<<dim3((NT+63)/64, 3, BB), dim3(256), 0, stream>>>(x, flagp, Wf, out);
  }
}

// Round 9
// 656.866 us; speedup vs baseline: 1.0496x; 1.0329x over previous
//
#include <hip/hip_runtime.h>
#include <hip/hip_bf16.h>

#define BB 32
#define CC 64
#define NN 307
#define TT 24
#define CO 192
#define NT (NN*TT)   // 7368
#define GO 1536      // CC*TT

using bf16 = __hip_bfloat16;
typedef __attribute__((ext_vector_type(8))) short bf16x8;
typedef __attribute__((ext_vector_type(4))) float f32x4;

// fp32 weight-arena offsets (element = float)
#define OFF_ln_g   0
#define OFF_ln_b   24
#define OFF_res_W  48
#define OFF_res_b  12336
#define OFF_ca_W1  12528
#define OFF_ca_W2  12552
#define OFF_ca_W3  19920
#define OFF_cc_W   20227
#define OFF_cc_b   24323
#define OFF_ta_W1  24387
#define OFF_ta_W2  24694
#define OFF_ta_W3  44342
#define OFF_tc_W0  44406
#define OFF_tc_b0  52598
#define OFF_tc_W1  52662
#define OFF_tc_b1  60854
#define OFF_ga_W1  60918
#define OFF_ga_W2  60942
#define OFF_ga_W3  62478
#define OFF_g_W    62542
#define W_TOTAL    66638

__device__ __forceinline__ float xload(const void* p, size_t i, int f) {
  return f ? ((const float*)p)[i] : __bfloat162float(((const bf16*)p)[i]);
}
__device__ __forceinline__ void ostore(void* p, size_t i, float v, int f) {
  if (f) ((float*)p)[i] = v; else ((bf16*)p)[i] = __float2bfloat16(v);
}
__device__ __forceinline__ float oload(const void* p, size_t i, int f) {
  return f ? ((const float*)p)[i] : __bfloat162float(((const bf16*)p)[i]);
}

__global__ void MEAM_44787918963464_kernel() {}

// ---- 0b. convert all small weights to fp32 arena (inline dtype probe from p0 = ln_g)
__global__ __launch_bounds__(256) void k_cvt_w(
    const void* p0, const void* p1, const void* p2, const void* p3,
    const void* p4, const void* p5, const void* p6, const void* p7,
    const void* p8, const void* p9, const void* p10, const void* p11,
    const void* p12, const void* p13, const void* p14, const void* p15,
    const void* p16, const void* p17, const void* p18, const void* p19,
    int* flagp, float* dst) {
  int i = blockIdx.x*256 + threadIdx.x;
  unsigned w0 = *(const unsigned*)p0;
  int f = (w0 == 0x3F800000u) ? 1 : 0;
  if (i == 0) *flagp = f;
  if (i >= W_TOTAL) return;
  const void* ps[20] = {p0,p1,p2,p3,p4,p5,p6,p7,p8,p9,p10,p11,p12,p13,p14,p15,p16,p17,p18,p19};
  const int sz[20] = {24,24,12288,192,24,7368,307,4096,64,307,19648,64,8192,64,8192,64,24,1536,64,4096};
  int s = 0, base = 0;
  while (i >= base + sz[s]) { base += sz[s]; s++; }
  dst[i] = f ? ((const float*)ps[s])[i-base]
             : __bfloat162float(((const bf16*)ps[s])[i-base]);
}

// ---- 0c. composed t-branch conv matrices (4 taps) + residual tap + biases
__global__ __launch_bounds__(256) void k_prep_tc(const float* __restrict__ W,
    bf16* __restrict__ Ag, float* __restrict__ tb_bias) {
  int g = blockIdx.x*256 + threadIdx.x;
  if (g >= CC*CC) return;
  int pI = g >> 6, c = g & 63;
  const float* W0 = W + OFF_tc_W0;
  const float* b0 = W + OFF_tc_b0;
  const float* W1 = W + OFF_tc_W1;
  const float* b1 = W + OFF_tc_b1;
  const float* resW = W + OFF_res_W;
  const float* resb = W + OFF_res_b;
  float m0=0.f,m1=0.f,m2=0.f,m3=0.f, bb0=0.f, bb2=0.f;
  for (int o=0;o<CC;o++){
    float a1v = W1[(pI*CC+o)*2], b1v = W1[(pI*CC+o)*2+1];
    float a0v = W0[(o*CC+c)*2],  b0v = W0[(o*CC+c)*2+1];
    m0 += b1v*b0v; m1 += b1v*a0v; m2 += a1v*b0v; m3 += a1v*a0v;
    bb0 += b1v*b0[o]; bb2 += a1v*b0[o];
  }
  Ag[pI*320 + 0*64 + c] = __float2bfloat16(m0);
  Ag[pI*320 + 1*64 + c] = __float2bfloat16(m1);
  Ag[pI*320 + 2*64 + c] = __float2bfloat16(m2);
  Ag[pI*320 + 3*64 + c] = __float2bfloat16(m3);
  Ag[pI*320 + 4*64 + c] = __float2bfloat16(resW[(64+pI)*CC + c]);
  if (c == 0){
    tb_bias[pI]    = b1[pI] + bb0 + resb[64+pI];
    tb_bias[64+pI] = bb2;
  }
}

// ---- 0d. Apre[b][192][128] bf16 = [[Mc|resW0..63],[gW|0],[0|resW128..191]]
__global__ __launch_bounds__(256) void k_prep_A(const float* __restrict__ Mc,
    const float* __restrict__ W, bf16* __restrict__ Apre) {
  int idx = blockIdx.x*256 + threadIdx.x;
  if (idx >= BB*192*128) return;
  int b = idx / 24576;
  int rem = idx - b*24576;
  int p2 = rem >> 7, k = rem & 127;
  const float* resW = W + OFF_res_W;
  const float* gW   = W + OFF_g_W;
  float v;
  if (p2 < 64)       v = (k < 64) ? Mc[b*CC*CC + p2*CC + k] : resW[p2*CC + (k-64)];
  else if (p2 < 128) v = (k < 64) ? gW[(p2-64)*CC + k] : 0.f;
  else               v = (k < 64) ? 0.f : resW[p2*CC + (k-64)];
  Apre[idx] = __float2bfloat16(v);
}

// ---- 1. FUSED LN + per-(b,c,t) reductions. One block per (b,c).
__global__ __launch_bounds__(256) void k_lnct(const void* __restrict__ x, const int* flagp,
    const float* __restrict__ W,
    float* __restrict__ mu_a, float* __restrict__ rs_a,
    float* __restrict__ xw1c, float* __restrict__ xw1g,
    float* __restrict__ lhsc, float* __restrict__ rhsc, float* __restrict__ xw1t) {
  int bc = blockIdx.x;            // (b*CC + c)
  int tid = threadIdx.x;
  int f = *flagp;
  const float* lng  = W + OFF_ln_g;
  const float* lnb  = W + OFF_ln_b;
  const float* caW1 = W + OFF_ca_W1;
  const float* gaW1 = W + OFF_ga_W1;
  const float* caW2 = W + OFF_ca_W2;
  const float* caW3 = W + OFF_ca_W3;
  const float* taW1 = W + OFF_ta_W1;
  __shared__ float xs[NN*25];     // 30.7KB, row-padded
  __shared__ float mus[NN], rss[NN], w1c[NN];
  __shared__ float red[3*240];
  size_t base = (size_t)bc * NT;
  if (f) {
    const float4* xp = (const float4*)((const float*)x + base);
    for (int e=tid; e<NT/4; e+=256){
      float4 q = xp[e];
      int n = e/6; int t0 = e*4 - n*24;
      float* d = &xs[n*25 + t0];
      d[0]=q.x; d[1]=q.y; d[2]=q.z; d[3]=q.w;
    }
  } else {
    const uint4* xp = (const uint4*)((const unsigned short*)x + base);
    for (int e=tid; e<NT/8; e+=256){
      uint4 q = xp[e]; unsigned u[4]={q.x,q.y,q.z,q.w};
      int n = e/3; int t0 = e*8 - n*24;
      float* d = &xs[n*25 + t0];
      #pragma unroll
      for (int k=0;k<4;k++){
        union{unsigned uu;float fl;} lo,hi;
        lo.uu=u[k]<<16; hi.uu=u[k]&0xffff0000u;
        d[k*2]=lo.fl; d[k*2+1]=hi.fl;
      }
    }
  }
  __syncthreads();
  for (int n=tid; n<NN; n+=256){
    const float* row = &xs[n*25];
    float mu=0.f;
    #pragma unroll
    for (int t=0;t<TT;t++) mu += row[t];
    mu *= (1.f/TT);
    float var=0.f;
    #pragma unroll
    for (int t=0;t<TT;t++){ float d=row[t]-mu; var += d*d; }
    var *= (1.f/TT);
    float rs = rsqrtf(var+1e-5f);
    float s1=0.f, s2=0.f;
    #pragma unroll
    for (int t=0;t<TT;t++){
      float hv=(row[t]-mu)*rs*lng[t]+lnb[t];
      s1+=hv*caW1[t]; s2+=hv*gaW1[t];
    }
    mus[n]=mu; rss[n]=rs; w1c[n]=s1;
    int gi = bc*NN+n;
    mu_a[gi]=mu; rs_a[gi]=rs; xw1c[gi]=s1; xw1g[gi]=s2;
  }
  __syncthreads();
  int t = tid % TT, g = tid / TT;   // 10 full n-groups (g<10)
  if (g < 10){
    float gt=lng[t], bt=lnb[t];
    float l=0.f, rr=0.f, xt=0.f;
    for (int n=g; n<NN; n+=10){
      float hv=(xs[n*25+t]-mus[n])*rss[n]*gt+bt;
      l += w1c[n]*caW2[n*TT+t];
      rr+= caW3[n]*hv;
      xt+= taW1[n]*hv;
    }
    red[g*TT+t]=l; red[240+g*TT+t]=rr; red[480+g*TT+t]=xt;
  }
  __syncthreads();
  if (tid < TT){
    float L=0.f,R=0.f,X=0.f;
    #pragma unroll
    for (int g2=0; g2<10; g2++){
      L+=red[g2*TT+tid]; R+=red[240+g2*TT+tid]; X+=red[480+g2*TT+tid];
    }
    lhsc[bc*TT+tid]=L; rhsc[bc*TT+tid]=R; xw1t[bc*TT+tid]=X;
  }
}

// ---- 3. per (b,n,t): rhs_t, rhs_g, lhs_g (reduce over c)  [r6 form]
__global__ __launch_bounds__(256) void k_prep_bn(const void* __restrict__ x, const int* flagp,
    const float* __restrict__ mu_a, const float* __restrict__ rs_a,
    const float* __restrict__ W, const float* __restrict__ xw1g,
    float* __restrict__ rhst, float* __restrict__ rhsg, float* __restrict__ lhsg) {
  int i = blockIdx.x*256 + threadIdx.x;     // (b*N+n)*T + t
  if (i >= BB*NN*TT) return;
  int f = *flagp;
  const float* lng  = W + OFF_ln_g;
  const float* lnb  = W + OFF_ln_b;
  const float* taW3 = W + OFF_ta_W3;
  const float* gaW3 = W + OFF_ga_W3;
  const float* gaW2 = W + OFF_ga_W2;
  int t = i % TT; int n = (i/TT)%NN; int b = i/(NN*TT);
  float gt = lng[t], bt = lnb[t];
  float a=0.f,c2=0.f,d=0.f;
  for (int c=0;c<CC;c++){
    int row = (b*CC+c)*NN + n;
    float hv = (xload(x, (size_t)row*TT+t, f) - mu_a[row]) * rs_a[row] * gt + bt;
    a  += taW3[c]*hv;
    c2 += gaW3[c]*hv;
    d  += xw1g[row]*gaW2[c*TT+t];
  }
  rhst[i]=a; rhsg[i]=c2; lhsg[i]=d;
}

// ---- 4. lhs_t[b,t,n] = sum_c xW1_t[b,c,t]*taW2[c,n]
__global__ __launch_bounds__(256) void k_lhs_t(const float* __restrict__ xw1t,
    const float* __restrict__ W, float* __restrict__ lhst) {
  int i = blockIdx.x*256 + threadIdx.x;     // (b*T+t)*N + n
  if (i >= BB*TT*NN) return;
  const float* taW2 = W + OFF_ta_W2;
  int n = i % NN; int t = (i/NN)%TT; int b = i/(TT*NN);
  float acc=0.f;
  for (int c=0;c<CC;c++)
    acc += xw1t[(b*CC+c)*TT+t]*taW2[c*NN+n];
  lhst[i]=acc;
}

// ---- 5. channel attention softmax folded with cc_W -> Mc[o][d]
__global__ __launch_bounds__(256) void k_att_c(const float* __restrict__ lhsc,
    const float* __restrict__ rhsc, const float* __restrict__ W,
    float* __restrict__ Mc) {
  int b = blockIdx.x; int tid = threadIdx.x;
  const float* ccW = W + OFF_cc_W;
  __shared__ float lc[CC*TT], rc[CC*TT], sc[CC*(CC+1)];
  for (int e=tid;e<CC*TT;e+=256){
    lc[e]=lhsc[b*CC*TT+e];
    rc[e]=rhsc[b*CC*TT+e];
  }
  __syncthreads();
  for (int e=tid;e<CC*CC;e+=256){
    int c=e>>6, d=e&63; float s=0.f;
    for (int t=0;t<TT;t++) s += lc[c*TT+t]*rc[d*TT+t];
    sc[c*(CC+1)+d]=s;
  }
  __syncthreads();
  if (tid<CC){
    float mx=-1e30f;
    for (int d=0;d<CC;d++) mx=fmaxf(mx, sc[tid*(CC+1)+d]);
    float sum=0.f;
    for (int d=0;d<CC;d++){ float e2=__expf(sc[tid*(CC+1)+d]-mx); sc[tid*(CC+1)+d]=e2; sum+=e2; }
    float inv=1.f/sum;
    for (int d=0;d<CC;d++) sc[tid*(CC+1)+d]*=inv;
  }
  __syncthreads();
  for (int e=tid;e<CC*CC;e+=256){
    int o=e>>6, d=e&63; float acc=0.f;
    for (int c=0;c<CC;c++) acc += ccW[o*CC+c]*sc[c*(CC+1)+d];
    Mc[b*CC*CC+e]=acc;
  }
}

// ---- 6. temporal attention 24x24 softmax
__global__ __launch_bounds__(256) void k_att_t(const float* __restrict__ lhst,
    const float* __restrict__ rhst, float* __restrict__ attt) {
  int b=blockIdx.x, tid=threadIdx.x;
  __shared__ float sc[TT*TT];
  for (int e=tid;e<TT*TT;e+=256){
    int t=e/TT, s=e%TT;
    float acc=0.f;
    for (int n=0;n<NN;n++)
      acc += lhst[(b*TT+t)*NN+n]*rhst[(b*NN+n)*TT+s];
    sc[e]=acc;
  }
  __syncthreads();
  if (tid < TT){
    float mx=-1e30f;
    for (int s=0;s<TT;s++) mx=fmaxf(mx,sc[tid*TT+s]);
    float sum=0.f;
    for (int s=0;s<TT;s++){ float e=__expf(sc[tid*TT+s]-mx); sc[tid*TT+s]=e; sum+=e; }
    float inv=1.f/sum;
    for (int s=0;s<TT;s++) attt[b*TT*TT + tid*TT + s]=sc[tid*TT+s]*inv;
  }
}

// ---- 7a1. graph attention scores via MFMA (hi/lo bf16 split for ~fp32 accuracy)
__global__ __launch_bounds__(256) void k_scores_g(const float* __restrict__ lhsg,
    const float* __restrict__ rhsg, const int* __restrict__ adj,
    float* __restrict__ Sg) {
  int mt = blockIdx.x, nt = blockIdx.y, b = blockIdx.z;
  int n0 = nt*64, m0 = mt*64, tid = threadIdx.x;
  __shared__ unsigned short Lh[64*40], Ll[64*40], Rh[64*40], Rl[64*40];
  for (int e=tid; e<64*24; e+=256){
    int r=e/24, t=e-(e/24)*24;
    int gn=n0+r, gm=m0+r;
    float lv = (gn<NN)? lhsg[((size_t)b*NN+gn)*TT+t] : 0.f;
    float rv = (gm<NN)? rhsg[((size_t)b*NN+gm)*TT+t] : 0.f;
    bf16 lh=__float2bfloat16(lv); float lhf=__bfloat162float(lh);
    bf16 llo=__float2bfloat16(lv-lhf);
    bf16 rh=__float2bfloat16(rv); float rhf=__bfloat162float(rh);
    bf16 rlo=__float2bfloat16(rv-rhf);
    Lh[r*40+t]=*(unsigned short*)&lh; Ll[r*40+t]=*(unsigned short*)&llo;
    Rh[r*40+t]=*(unsigned short*)&rh; Rl[r*40+t]=*(unsigned short*)&rlo;
  }
  for (int e=tid; e<64*8; e+=256){
    int r=e>>3, t=24+(e&7);
    Lh[r*40+t]=0; Ll[r*40+t]=0; Rh[r*40+t]=0; Rl[r*40+t]=0;
  }
  __syncthreads();
  int lane=tid&63, w=tid>>6, q=lane>>4, lr=lane&15;
  bf16x8 ah = *(const bf16x8*)&Lh[(w*16+lr)*40 + q*8];
  bf16x8 al = *(const bf16x8*)&Ll[(w*16+lr)*40 + q*8];
  f32x4 z4={0.f,0.f,0.f,0.f};
  f32x4 acc[4]={z4,z4,z4,z4};
  #pragma unroll
  for (int ct=0;ct<4;ct++){
    bf16x8 bh = *(const bf16x8*)&Rh[(ct*16+lr)*40 + q*8];
    bf16x8 bl = *(const bf16x8*)&Rl[(ct*16+lr)*40 + q*8];
    acc[ct]=__builtin_amdgcn_mfma_f32_16x16x32_bf16(ah,bh,acc[ct],0,0,0);
    acc[ct]=__builtin_amdgcn_mfma_f32_16x16x32_bf16(ah,bl,acc[ct],0,0,0);
    acc[ct]=__builtin_amdgcn_mfma_f32_16x16x32_bf16(al,bh,acc[ct],0,0,0);
  }
  #pragma unroll
  for (int ct=0;ct<4;ct++){
    int m = m0 + ct*16 + lr;
    #pragma unroll
    for (int r=0;r<4;r++){
      int n = n0 + w*16 + q*4 + r;
      if (n<NN && m<NN){
        float s = acc[ct][r];
        if (adj[n*NN+m] <= 0) s = -1e30f;
        Sg[((size_t)b*NN+n)*NN+m] = s;
      }
    }
  }
}

// ---- 7a2. row softmax of Sg -> attgh bf16. One wave per row, shfl reductions.
__global__ __launch_bounds__(256) void k_smax_g(const float* __restrict__ Sg,
    bf16* __restrict__ attgh) {
  int b = blockIdx.y;
  int n = blockIdx.x*4 + (threadIdx.x>>6);
  int lane = threadIdx.x & 63;
  if (n >= NN) return;
  const float* row = Sg + ((size_t)b*NN+n)*NN;
  float v[5]; float mx = -1e30f;
  #pragma unroll
  for (int i=0;i<5;i++){
    int m = lane + i*64;
    v[i] = (m<NN)? row[m] : -1e30f;
    mx = fmaxf(mx, v[i]);
  }
  #pragma unroll
  for (int off=32; off; off>>=1) mx = fmaxf(mx, __shfl_xor(mx, off));
  float sum = 0.f;
  #pragma unroll
  for (int i=0;i<5;i++){
    int m = lane + i*64;
    float e = (m<NN)? __expf(v[i]-mx) : 0.f;
    v[i]=e; sum += e;
  }
  #pragma unroll
  for (int off=32; off; off>>=1) sum += __shfl_xor(sum, off);
  float inv = 1.f/sum;
  bf16* orow = attgh + ((size_t)b*NN+n)*NN;
  #pragma unroll
  for (int i=0;i<5;i++){
    int m = lane + i*64;
    if (m<NN) orow[m] = __float2bfloat16(v[i]*inv);
  }
}

// ---- 7b. fused c-branch + residual(0..63) + hg + residual(128..191 -> resg bf16) via MFMA.
__global__ __launch_bounds__(256) void k_hgc_mfma(
    const void* __restrict__ x, const int* flagp,
    const float* __restrict__ mu_a, const float* __restrict__ rs_a,
    const float* __restrict__ W, const bf16* __restrict__ Apre,
    bf16* __restrict__ hg, bf16* __restrict__ resg, void* __restrict__ out) {
  int jt = blockIdx.x, b = blockIdx.y, tid = threadIdx.x;
  int f = *flagp;
  int j0 = jt*64;
  const float* lng = W + OFF_ln_g;
  const float* lnb = W + OFF_ln_b;
  const float* ccb = W + OFF_cc_b;
  const float* resb= W + OFF_res_b;
  __shared__ unsigned short Bs[64*128];   // [j][k] bf16, 16KB

  {
    int c = tid >> 2, jg = tid & 3;
    float xv[16];
    int jbase = j0 + jg*16;
    size_t xoff = (size_t)(b*CC + c)*NT + jbase;
    if (jbase + 15 < NT) {
      if (f) {
        const float4* xp = (const float4*)((const float*)x + xoff);
        #pragma unroll
        for (int v=0; v<4; v++){ float4 q = xp[v]; xv[v*4]=q.x; xv[v*4+1]=q.y; xv[v*4+2]=q.z; xv[v*4+3]=q.w; }
      } else {
        const uint4* xp = (const uint4*)((const unsigned short*)x + xoff);
        #pragma unroll
        for (int v=0; v<2; v++){
          uint4 q = xp[v]; unsigned u[4]={q.x,q.y,q.z,q.w};
          #pragma unroll
          for (int kk2=0;kk2<4;kk2++){
            union{unsigned uu;float fl;} lo,hi;
            lo.uu=u[kk2]<<16; hi.uu=u[kk2]&0xffff0000u;
            xv[v*8+kk2*2]=lo.fl; xv[v*8+kk2*2+1]=hi.fl;
          }
        }
      }
    } else {
      #pragma unroll
      for (int i=0;i<16;i++){ int j=jbase+i; xv[i] = (j<NT)? xload(x, xoff+i, f) : 0.f; }
    }
    const float* mu_r = mu_a + (b*CC+c)*NN;
    const float* rs_r = rs_a + (b*CC+c)*NN;
    #pragma unroll
    for (int i=0;i<16;i++){
      int j = jbase + i;
      int jl = jg*16 + i;
      float hv = 0.f, xf = 0.f;
      if (j < NT){
        int n = j / 24, t = j - n*24;
        xf = xv[i];
        hv = (xf - mu_r[n]) * rs_r[n] * lng[t] + lnb[t];
      }
      int cs = c ^ ((jl&7)<<3);
      bf16 hb = __float2bfloat16(hv), xb = __float2bfloat16(xf);
      Bs[jl*128 + cs]      = *(unsigned short*)&hb;
      Bs[jl*128 + cs + 64] = *(unsigned short*)&xb;
    }
  }

  int lane = tid & 63, w = tid >> 6;
  int q = lane >> 4, lr = lane & 15;
  bf16x8 afo[4], afh[2], afr[2];
  {
    const unsigned short* Ab = (const unsigned short*)Apre + (size_t)b*24576;
    const unsigned short* r0 = Ab + (w*16 + lr)*128;
    #pragma unroll
    for (int kc=0;kc<4;kc++) afo[kc] = *(const bf16x8*)&r0[kc*32 + q*8];
    const unsigned short* r1 = Ab + (64 + w*16 + lr)*128;
    #pragma unroll
    for (int kc=0;kc<2;kc++) afh[kc] = *(const bf16x8*)&r1[kc*32 + q*8];
    const unsigned short* r2 = Ab + (128 + w*16 + lr)*128;
    #pragma unroll
    for (int kc=0;kc<2;kc++) afr[kc] = *(const bf16x8*)&r2[(kc+2)*32 + q*8];
  }
  f32x4 z4 = {0.f,0.f,0.f,0.f};
  f32x4 acco[4] = {z4,z4,z4,z4};
  f32x4 acch[4] = {z4,z4,z4,z4};
  f32x4 accr[4] = {z4,z4,z4,z4};
  __syncthreads();

  #pragma unroll
  for (int ct=0; ct<4; ct++){
    int jl = ct*16 + lr;
    int sw = ((jl&7)<<3);
    #pragma unroll
    for (int kc=0; kc<4; kc++){
      int ke = (kc*32 + q*8) ^ sw;
      bf16x8 bfr = *(const bf16x8*)&Bs[jl*128 + ke];
      acco[ct] = __builtin_amdgcn_mfma_f32_16x16x32_bf16(afo[kc], bfr, acco[ct], 0,0,0);
      if (kc < 2)
        acch[ct] = __builtin_amdgcn_mfma_f32_16x16x32_bf16(afh[kc], bfr, acch[ct], 0,0,0);
      else
        accr[ct] = __builtin_amdgcn_mfma_f32_16x16x32_bf16(afr[kc-2], bfr, accr[ct], 0,0,0);
    }
  }

  #pragma unroll
  for (int ct=0;ct<4;ct++){
    int jl = ct*16 + lr;
    int j = j0 + jl;
    if (j < NT){
      #pragma unroll
      for (int r=0;r<4;r++){
        int p2 = w*16 + q*4 + r;
        float v = acco[ct][r] + ccb[p2] + resb[p2];
        ostore(out, ((size_t)b*CO + p2)*NT + j, fmaxf(v,0.f), f);
      }
      int n = j/24, t2 = j - n*24;
      size_t hb2 = ((size_t)b*NN + n)*GO + t2;
      #pragma unroll
      for (int r=0;r<4;r++){
        int o = w*16 + q*4 + r;
        hg[hb2 + o*TT] = __float2bfloat16(acch[ct][r]);
      }
      #pragma unroll
      for (int r=0;r<4;r++){
        int p3 = w*16 + q*4 + r;
        resg[((size_t)b*CC + p3)*NT + j] = __float2bfloat16(accr[ct][r] + resb[128+p3]);
      }
    }
  }
}

// ---- 7c. graph GEMM, MFMA bf16: out[128+o] = relu(attg@hg + resg)
__global__ __launch_bounds__(256) void k_gemm_g(const bf16* __restrict__ attgh,
    const bf16* __restrict__ hg, const bf16* __restrict__ resg,
    const int* flagp, void* __restrict__ out) {
  int jt = blockIdx.x, nt = blockIdx.y, b = blockIdx.z;
  int tid = threadIdx.x;
  int f = *flagp;
  int n0 = nt*64, j0 = jt*64;
  __shared__ unsigned short As[64*72];
  __shared__ unsigned short Bs[64*72];
  int lane = tid & 63, w = tid >> 6;
  int q = lane >> 4, lr = lane & 15;
  f32x4 z4 = {0.f,0.f,0.f,0.f};
  f32x4 acc[4] = {z4,z4,z4,z4};
  const unsigned short* Ag = (const unsigned short*)attgh + (size_t)b*NN*NN;
  const unsigned short* Bg = (const unsigned short*)hg + (size_t)b*NN*GO;
  for (int m0=0;m0<NN;m0+=64){
    for (int u=tid; u<512; u+=256){
      int r=u>>3, kb=(u&7)*8;
      int gn=n0+r, gm=m0+kb;
      if (gn<NN && gm+7<NN){
        *(uint4*)&As[r*72+kb] = *(const uint4*)&Ag[(size_t)gn*NN + gm];
      } else {
        for (int i2=0;i2<8;i2++){
          int m=gm+i2;
          As[r*72+kb+i2] = (gn<NN && m<NN) ? Ag[(size_t)gn*NN+m] : 0;
        }
      }
    }
    for (int u=tid; u<512; u+=256){
      int m = u>>3, jb = (u&7)*8;       // coalesced: 8 lanes read 128B of row gm
      int gm = m0 + m;
      unsigned short s[8];
      if (gm < NN){
        *(uint4*)s = *(const uint4*)&Bg[(size_t)gm*GO + j0 + jb];
      } else {
        #pragma unroll
        for (int i2=0;i2<8;i2++) s[i2]=0;
      }
      int mb = m>>3, ml2 = m&7;
      #pragma unroll
      for (int i2=0;i2<8;i2++){
        int j = jb + i2;
        int col = ((mb ^ (j>>3)) << 3) | ml2;
        Bs[j*72 + col] = s[i2];
      }
    }
    __syncthreads();
    #pragma unroll
    for (int kk=0;kk<64;kk+=32){
      bf16x8 af = *(const bf16x8*)&As[(w*16+lr)*72 + kk + q*8];
      #pragma unroll
      for (int ct=0;ct<4;ct++){
        int jrow = ct*16+lr;
        int kb = kk + q*8;
        int col = (((kb>>3) ^ (jrow>>3)) << 3);
        bf16x8 bfr = *(const bf16x8*)&Bs[jrow*72 + col];
        acc[ct] = __builtin_amdgcn_mfma_f32_16x16x32_bf16(af, bfr, acc[ct], 0,0,0);
      }
    }
    __syncthreads();
  }
  #pragma unroll
  for (int ct=0;ct<4;ct++){
    #pragma unroll
    for (int r=0;r<4;r++){
      int n = n0 + w*16 + q*4 + r;
      if (n >= NN) continue;
      int j = j0 + ct*16 + lr;
      int o = j/TT, t2 = j%TT;
      size_t idx = ((size_t)b*CO + 128 + o)*NT + (size_t)n*TT + t2;
      float v = acc[ct][r] + __bfloat162float(resg[((size_t)b*CC + o)*NT + (size_t)n*TT + t2]);
      ostore(out, idx, fmaxf(v, 0.f), f);
    }
  }
}

// ---- 8f. FALLBACK c-branch (raw write)
__global__ __launch_bounds__(256) void k_cmix(const float* __restrict__ Mc,
    const void* __restrict__ x, const int* flagp,
    const float* __restrict__ mu_a, const float* __restrict__ rs_a,
    const float* __restrict__ W, void* __restrict__ out) {
  int jt=blockIdx.x, b=blockIdx.y, tid=threadIdx.x;
  int f = *flagp;
  int j0=jt*64;
  const float* lng = W + OFF_ln_g;
  const float* lnb = W + OFF_ln_b;
  const float* ccb = W + OFF_cc_b;
  __shared__ float Ms[CC*64];
  __shared__ float Hs[CC*64];
  for (int e=tid;e<CC*64;e+=256){
    int o=e&63, d=e>>6;
    Ms[e]=Mc[b*CC*CC + o*CC + d];
  }
  for (int e=tid;e<CC*64;e+=256){
    int d=e>>6, j=e&63; int jj=j0+j;
    float hv = 0.f;
    if (jj<NT){
      int n = jj/TT, t = jj%TT;
      int row = (b*CC+d)*NN + n;
      hv = (xload(x, (size_t)(b*CC+d)*NT + jj, f) - mu_a[row]) * rs_a[row] * lng[t] + lnb[t];
    }
    Hs[e]=hv;
  }
  __syncthreads();
  int ti=tid&15, tj=tid>>4;
  float acc[4][4]={};
  for (int d=0;d<CC;d++){
    float4 a4=*(const float4*)&Ms[d*64+ti*4];
    float4 b4=*(const float4*)&Hs[d*64+tj*4];
    float av[4]={a4.x,a4.y,a4.z,a4.w};
    float bv[4]={b4.x,b4.y,b4.z,b4.w};
    for (int i=0;i<4;i++)
      for (int j=0;j<4;j++) acc[i][j]+=av[i]*bv[j];
  }
  for (int i=0;i<4;i++){
    int o=ti*4+i; float bias=ccb[o];
    for (int j=0;j<4;j++){
      int jj=j0+tj*4+j;
      if (jj<NT)
        ostore(out, ((size_t)b*CO+o)*NT+jj, acc[i][j]+bias, f);
    }
  }
}

// ---- 8g. FALLBACK fused g-branch
__global__ __launch_bounds__(256) void k_graph(const float* __restrict__ lhsg,
    const float* __restrict__ rhsg, const int* __restrict__ adj,
    const void* __restrict__ x, const int* flagp,
    const float* __restrict__ mu_a, const float* __restrict__ rs_a,
    const float* __restrict__ W, void* __restrict__ out) {
  int n = blockIdx.x, b = blockIdx.y, tid = threadIdx.x;
  int f = *flagp;
  const float* lng = W + OFF_ln_g;
  const float* lnb = W + OFF_ln_b;
  const float* gW  = W + OFF_g_W;
  __shared__ float ls[TT];
  __shared__ float sv[NN];
  __shared__ float red[256];
  __shared__ float wl[NN];
  __shared__ int   ml[NN];
  __shared__ int   cnt;
  __shared__ float z[CC*TT];
  __shared__ float Gs[CC*CC];
  __shared__ float gs[TT], bs[TT];
  if (tid < TT){
    ls[tid] = lhsg[(b*NN+n)*TT + tid];
    gs[tid] = lng[tid]; bs[tid] = lnb[tid];
  }
  for (int e=tid;e<CC*CC;e+=256) Gs[e]=gW[e];
  __syncthreads();
  float lmax = -1e30f;
  for (int m=tid;m<NN;m+=256){
    float s = -1e30f;
    if (adj[n*NN+m] > 0){
      const float* rr = rhsg + ((size_t)b*NN+m)*TT;
      float acc=0.f;
      for (int t=0;t<TT;t++) acc += ls[t]*rr[t];
      s = acc;
    }
    sv[m]=s; lmax=fmaxf(lmax,s);
  }
  red[tid]=lmax; __syncthreads();
  for (int k=128;k>0;k>>=1){ if (tid<k) red[tid]=fmaxf(red[tid],red[tid+k]); __syncthreads(); }
  float mx = red[0]; __syncthreads();
  float lsum=0.f;
  for (int m=tid;m<NN;m+=256){
    float e = (sv[m] > -1e29f) ? __expf(sv[m]-mx) : 0.f;
    sv[m]=e; lsum+=e;
  }
  red[tid]=lsum; __syncthreads();
  for (int k=128;k>0;k>>=1){ if (tid<k) red[tid]+=red[tid+k]; __syncthreads(); }
  float inv = 1.f/red[0];
  if (tid==0){
    int c=0;
    for (int m=0;m<NN;m++) if (sv[m]!=0.f){ ml[c]=m; wl[c]=sv[m]*inv; c++; }
    cnt=c;
  }
  __syncthreads();
  int K = cnt;
  {
    int c = tid>>2, tg = tid&3;
    float acc[6]={0,0,0,0,0,0};
    float s0 = 0.f;
    const float* mu_r = mu_a + (b*CC+c)*NN;
    const float* rs_r = rs_a + (b*CC+c)*NN;
    size_t xbase = (size_t)(b*CC+c)*NT;
    for (int k=0;k<K;k++){
      int m = ml[k];
      float wr = wl[k]*rs_r[m];
      s0 += wr*mu_r[m];
      size_t xm = xbase + m*TT + tg*6;
      for (int j=0;j<6;j++) acc[j] += wr*xload(x, xm+j, f);
    }
    for (int j=0;j<6;j++){
      int t = tg*6+j;
      z[c*TT+t] = gs[t]*(acc[j]-s0) + bs[t];
    }
  }
  __syncthreads();
  {
    int o = tid>>2, tg = tid&3;
    float acc[6]={0,0,0,0,0,0};
    for (int c=0;c<CC;c++){
      float gwv = Gs[o*CC+c];
      const float* zr = &z[c*TT + tg*6];
      for (int j=0;j<6;j++) acc[j] += gwv*zr[j];
    }
    size_t base = ((size_t)b*CO + 128 + o)*NT + n*TT + tg*6;
    for (int j=0;j<6;j++)
      ostore(out, base+j, acc[j], f);
  }
}

// ---- 9. FALLBACK t-branch
__global__ __launch_bounds__(256) void k_tbranch(const void* __restrict__ x, const int* flagp,
    const float* __restrict__ mu_a, const float* __restrict__ rs_a,
    const float* __restrict__ W, const float* __restrict__ attt,
    void* __restrict__ out, int fuse) {
  int chunk = blockIdx.x, b = blockIdx.y, tid = threadIdx.x;
  int f = *flagp;
  int n0 = chunk*4;
  const float* lng = W + OFF_ln_g;
  const float* lnb = W + OFF_ln_b;
  const float* W0  = W + OFF_tc_W0;
  const float* b0  = W + OFF_tc_b0;
  const float* W1  = W + OFF_tc_W1;
  const float* b1  = W + OFF_tc_b1;
  __shared__ float hs[256*25];
  __shared__ float at[TT*TT];
  for (int e=tid;e<CC*4*TT;e+=256){
    int c=e/(4*TT), rem=e%(4*TT), i=rem/TT, t=rem%TT;
    int n=n0+i;
    float hv=0.f;
    if (n<NN){
      int row=(b*CC+c)*NN+n;
      hv = (xload(x,(size_t)row*TT+t,f) - mu_a[row]) * rs_a[row] * lng[t] + lnb[t];
    }
    hs[(c*4+i)*25+t] = hv;
  }
  for (int e=tid;e<TT*TT;e+=256) at[e]=attt[b*TT*TT+e];
  __syncthreads();
  {
    float r[TT], o2[TT];
    float* myrow = &hs[tid*25];
    #pragma unroll
    for (int s=0;s<TT;s++) r[s]=myrow[s];
    for (int t=0;t<TT;t++){
      float a=0.f;
      #pragma unroll
      for (int s=0;s<TT;s++) a += at[t*TT+s]*r[s];
      o2[t]=a;
    }
    #pragma unroll
    for (int t=0;t<TT;t++) myrow[t]=o2[t];
  }
  __syncthreads();
  {
    int o = tid>>2, i = tid&3;
    float acc[TT];
    float bb = b0[o];
    for (int t=0;t<TT;t++) acc[t]=bb;
    for (int c=0;c<CC;c++){
      float wa = W0[(o*CC+c)*2], wb = W0[(o*CC+c)*2+1];
      const float* row = &hs[(c*4+i)*25];
      acc[0] += wb*row[0];
      #pragma unroll
      for (int t=1;t<TT;t++) acc[t] += wa*row[t-1] + wb*row[t];
    }
    __syncthreads();
    float* myrow = &hs[tid*25];
    #pragma unroll
    for (int t=0;t<TT;t++) myrow[t]=acc[t];
  }
  __syncthreads();
  {
    int o2 = tid>>2, i = tid&3;
    int n = n0+i;
    float acc[TT];
    float bb = b1[o2];
    for (int t=0;t<TT;t++) acc[t]=bb;
    for (int o=0;o<CC;o++){
      float wa = W1[(o2*CC+o)*2], wb = W1[(o2*CC+o)*2+1];
      const float* row = &hs[(o*4+i)*25];
      acc[0] += wb*row[0];
      acc[1] += wb*row[1];
      #pragma unroll
      for (int t=2;t<TT;t++) acc[t] += wa*row[t-2] + wb*row[t];
    }
    if (n<NN){
      size_t base = (((size_t)b*CO + 64 + o2)*NN + n)*TT;
      if (fuse){
        for (int t=0;t<TT;t++){
          float v = acc[t] + oload(out, base+t, f);
          ostore(out, base+t, fmaxf(v,0.f), f);
        }
      } else {
        for (int t=0;t<TT;t++) ostore(out, base+t, acc[t], f);
      }
    }
  }
}

// ---- 9m. t-branch via MFMA: composed 4-tap conv GEMM + fused residual tap, final write.
__device__ __forceinline__ void tb_load_raw(const void* __restrict__ x, int f, int b, int c, int nn,
    float* h) {
  if (nn < NN) {
    size_t off = (size_t)(b*CC + c)*NT + (size_t)nn*TT;
    if (f) {
      const float4* xp = (const float4*)((const float*)x + off);
      #pragma unroll
      for (int v=0; v<6; v++){
        float4 q = xp[v];
        h[v*4+0]=q.x; h[v*4+1]=q.y; h[v*4+2]=q.z; h[v*4+3]=q.w;
      }
    } else {
      const uint4* xp = (const uint4*)((const unsigned short*)x + off);
      #pragma unroll
      for (int v=0; v<3; v++){
        uint4 q = xp[v];
        unsigned wsv[4] = {q.x,q.y,q.z,q.w};
        #pragma unroll
        for (int k=0;k<4;k++){
          union { unsigned u; float fl; } lo, hi;
          lo.u = wsv[k] << 16; hi.u = wsv[k] & 0xffff0000u;
          h[v*8 + k*2] = lo.fl; h[v*8 + k*2 + 1] = hi.fl;
        }
      }
    }
  } else {
    #pragma unroll
    for (int t=0;t<TT;t++) h[t]=0.f;
  }
}

__global__ __launch_bounds__(256) void k_tb_mfma(
    const void* __restrict__ x, const int* flagp,
    const float* __restrict__ mu_a, const float* __restrict__ rs_a,
    const float* __restrict__ W, const float* __restrict__ attt,
    const bf16* __restrict__ Agm, const float* __restrict__ tb_bias,
    void* __restrict__ out) {
  int chunk = blockIdx.x, b = blockIdx.y, tid = threadIdx.x;
  int f = *flagp;
  int n0 = chunk*8;
  const float* lng = W + OFF_ln_g;
  const float* lnb = W + OFF_ln_b;
  __shared__ unsigned short Bs[8*27*64];   // h' [n][s][c], s=t+3, 27648B
  __shared__ unsigned short Xs[8*24*64];   // raw x [n][t][c], 24576B

  for (int e=tid; e<8*3*64; e+=256){
    int n = e/192, rem = e%192, s = rem>>6, cz = rem&63;
    Bs[((n*27+s)<<6) + cz] = 0;
  }

  int c  = tid & 63;
  int nA = tid >> 6;
  float h0[TT], h1[TT];
  tb_load_raw(x, f, b, c, n0+nA,   h0);
  tb_load_raw(x, f, b, c, n0+nA+4, h1);
  #pragma unroll
  for (int t=0;t<TT;t++){
    int cs = c ^ ((t&7)<<3);
    bf16 v0 = __float2bfloat16(h0[t]);
    bf16 v1 = __float2bfloat16(h1[t]);
    Xs[(nA*24+t)*64 + cs]     = *reinterpret_cast<unsigned short*>(&v0);
    Xs[((nA+4)*24+t)*64 + cs] = *reinterpret_cast<unsigned short*>(&v1);
  }
  {
    int nn0 = n0+nA, nn1 = n0+nA+4;
    if (nn0 < NN){
      int r = (b*CC+c)*NN + nn0; float mu = mu_a[r], rs = rs_a[r];
      #pragma unroll
      for (int t=0;t<TT;t++) h0[t] = (h0[t]-mu)*rs*lng[t] + lnb[t];
    }
    if (nn1 < NN){
      int r = (b*CC+c)*NN + nn1; float mu = mu_a[r], rs = rs_a[r];
      #pragma unroll
      for (int t=0;t<TT;t++) h1[t] = (h1[t]-mu)*rs*lng[t] + lnb[t];
    }
  }
  const float* att_b = attt + b*TT*TT;
  for (int t=0;t<TT;t++){
    float a0=0.f, a1=0.f;
    #pragma unroll
    for (int s=0;s<TT;s++){
      float wv = att_b[t*TT+s];
      a0 += wv*h0[s]; a1 += wv*h1[s];
    }
    int sI = t+3;
    int cs = c ^ ((sI&7)<<3);
    bf16 v0 = __float2bfloat16(a0);
    bf16 v1 = __float2bfloat16(a1);
    Bs[((nA*27+sI)<<6) + cs]     = *reinterpret_cast<unsigned short*>(&v0);
    Bs[(((nA+4)*27+sI)<<6) + cs] = *reinterpret_cast<unsigned short*>(&v1);
  }

  int lane = tid & 63, w = tid >> 6;
  int q = lane >> 4, lr = lane & 15;
  bf16x8 af[10];
  const unsigned short* Arow = (const unsigned short*)Agm + (size_t)(w*16+lr)*320;
  #pragma unroll
  for (int kc=0;kc<10;kc++)
    af[kc] = *(const bf16x8*)&Arow[kc*32 + q*8];

  f32x4 z4 = {0.f,0.f,0.f,0.f};
  f32x4 acc[12] = {z4,z4,z4,z4,z4,z4,z4,z4,z4,z4,z4,z4};
  __syncthreads();

  #pragma unroll
  for (int ct=0; ct<12; ct++){
    int col = ct*16 + lr;
    int nl = col/24, t = col - nl*24;
    #pragma unroll
    for (int kc=0;kc<8;kc++){
      int tap = kc>>1;
      int s = t + 3 - tap;
      int cb = ((kc&1)*32 + q*8) ^ ((s&7)<<3);
      bf16x8 bfr = *(const bf16x8*)&Bs[((nl*27+s)<<6) + cb];
      acc[ct] = __builtin_amdgcn_mfma_f32_16x16x32_bf16(af[kc], bfr, acc[ct], 0,0,0);
    }
    #pragma unroll
    for (int kc2=0;kc2<2;kc2++){
      int cb = (kc2*32 + q*8) ^ ((t&7)<<3);
      bf16x8 bfr = *(const bf16x8*)&Xs[(nl*24+t)*64 + cb];
      acc[ct] = __builtin_amdgcn_mfma_f32_16x16x32_bf16(af[8+kc2], bfr, acc[ct], 0,0,0);
    }
  }

  #pragma unroll
  for (int ct=0;ct<12;ct++){
    int col = ct*16 + lr;
    int nl = col/24, t = col - nl*24;
    int nn = n0 + nl;
    if (nn < NN){
      #pragma unroll
      for (int r=0;r<4;r++){
        int pI = w*16 + q*4 + r;
        size_t idx = ((size_t)b*CO + 64 + pI)*NT + (size_t)nn*TT + t;
        float v = acc[ct][r] + tb_bias[pI] + (t>=2 ? tb_bias[64+pI] : 0.f);
        ostore(out, idx, fmaxf(v, 0.f), f);
      }
    }
  }
}

// ---- 10. FALLBACK final: out = relu(out + res_W@x + res_b)
__global__ __launch_bounds__(256) void k_res_final(const void* __restrict__ x, const int* flagp,
    const float* __restrict__ W, void* __restrict__ out) {
  int jt=blockIdx.x, ot=blockIdx.y, b=blockIdx.z; int tid=threadIdx.x;
  int f = *flagp;
  int j0=jt*64, o0=ot*64;
  const float* resW = W + OFF_res_W;
  const float* resb = W + OFF_res_b;
  __shared__ float Ws[CC*64];
  __shared__ float Xs[CC*64];
  for (int e=tid;e<CC*64;e+=256){
    int o=e&63, c=e>>6;
    Ws[e] = resW[(o0+o)*CC + c];
  }
  for (int e=tid;e<CC*64;e+=256){
    int c=e>>6, j=e&63; int jj=j0+j;
    Xs[e] = (jj<NT) ? xload(x, (size_t)(b*CC+c)*NT + jj, f) : 0.f;
  }
  __syncthreads();
  int ti=tid&15, tj=tid>>4;
  float acc[4][4]={};
  for (int k=0;k<CC;k++){
    float4 a4=*(const float4*)&Ws[k*64+ti*4];
    float4 b4=*(const float4*)&Xs[k*64+tj*4];
    float av[4]={a4.x,a4.y,a4.z,a4.w};
    float bv[4]={b4.x,b4.y,b4.z,b4.w};
    for (int i=0;i<4;i++)
      for (int j=0;j<4;j++) acc[i][j]+=av[i]*bv[j];
  }
  for (int i=0;i<4;i++){
    int o=o0+ti*4+i; float bias=resb[o];
    for (int j=0;j<4;j++){
      int jj=j0+tj*4+j;
      if (jj<NT){
        size_t idx=((size_t)b*CO+o)*NT+jj;
        float v = acc[i][j] + bias + oload(out, idx, f);
        ostore(out, idx, fmaxf(v,0.f), f);
      }
    }
  }
}

extern "C" void kernel_launch(void* const* d_in, const int* in_sizes, int n_in,
                              void* d_out, int out_size, void* d_ws, size_t ws_size,
                              hipStream_t stream) {
  const void* x     = d_in[0];
  const int*  adj   = (const int*)d_in[1];
  void* out = d_out;

  float* p = (float*)d_ws;
  int*   flagp = (int*)p; p += 4;
  float* Wf  = p; p += W_TOTAL;
  float* mu_a = p; p += (size_t)BB*CC*NN;
  float* rs_a = p; p += (size_t)BB*CC*NN;
  float* xw1c = p; p += (size_t)BB*CC*NN;
  float* xw1g = p; p += (size_t)BB*CC*NN;
  float* xw1t = p; p += (size_t)BB*CC*TT;
  float* lhsc = p; p += (size_t)BB*CC*TT;
  float* rhsc = p; p += (size_t)BB*CC*TT;
  float* rhst = p; p += (size_t)BB*NN*TT;
  float* rhsg = p; p += (size_t)BB*NN*TT;
  float* lhsg = p; p += (size_t)BB*NN*TT;
  float* lhst = p; p += (size_t)BB*TT*NN;
  float* attt = p; p += (size_t)BB*TT*TT;
  float* Mc   = p; p += (size_t)BB*CC*CC;
  bf16*  Agm  = (bf16*)p; p += 10240;    // 64*320 bf16 composed conv+res matrices
  float* tb_bias = p; p += 128;          // bias0[64], bias2[64]
  bf16*  Apre = (bf16*)p; p += (size_t)BB*192*128/2;   // [b][192][128] bf16
  float* Sg   = p; p += (size_t)BB*NN*NN + 16;         // masked scores fp32
  bf16*  attgh = (bf16*)p; p += (size_t)BB*NN*NN/2 + 16;
  bf16*  resg = (bf16*)p; p += (size_t)BB*CC*NT/2 + 16; // rows 128..191 residual bf16
  bf16*  hg   = (bf16*)p;
  size_t need = ((char*)(hg + (size_t)BB*NN*GO)) - (char*)d_ws;
  bool gemm_path = (ws_size >= need);

  k_cvt_w<<<dim3((W_TOTAL+255)/256), dim3(256), 0, stream>>>(
      d_in[2], d_in[3], d_in[4], d_in[5], d_in[6], d_in[7], d_in[8], d_in[9],
      d_in[10], d_in[11], d_in[12], d_in[13], d_in[14], d_in[15], d_in[16],
      d_in[17], d_in[18], d_in[19], d_in[20], d_in[21], flagp, Wf);
  k_lnct<<<dim3(BB*CC), dim3(256), 0, stream>>>(x, flagp, Wf, mu_a, rs_a, xw1c, xw1g, lhsc, rhsc, xw1t);
  k_prep_bn<<<dim3((BB*NN*TT+255)/256), dim3(256), 0, stream>>>(x, flagp, mu_a, rs_a, Wf, xw1g, rhst, rhsg, lhsg);
  k_lhs_t<<<dim3((BB*TT*NN+255)/256), dim3(256), 0, stream>>>(xw1t, Wf, lhst);
  k_att_c<<<dim3(BB), dim3(256), 0, stream>>>(lhsc, rhsc, Wf, Mc);
  k_att_t<<<dim3(BB), dim3(256), 0, stream>>>(lhst, rhst, attt);
  if (gemm_path) {
    k_prep_tc<<<dim3(16), dim3(256), 0, stream>>>(Wf, Agm, tb_bias);
    k_prep_A<<<dim3((BB*192*128+255)/256), dim3(256), 0, stream>>>(Mc, Wf, Apre);
    int ntile = (NN+63)/64;
    k_scores_g<<<dim3(ntile, ntile, BB), dim3(256), 0, stream>>>(lhsg, rhsg, adj, Sg);
    k_smax_g<<<dim3((NN+3)/4, BB), dim3(256), 0, stream>>>(Sg, attgh);
    k_hgc_mfma<<<dim3((NT+63)/64, BB), dim3(256), 0, stream>>>(x, flagp, mu_a, rs_a, Wf, Apre, hg, resg, out);
    k_tb_mfma<<<dim3((NN+7)/8, BB), dim3(256), 0, stream>>>(x, flagp, mu_a, rs_a, Wf, attt, Agm, tb_bias, out);
    k_gemm_g<<<dim3(GO/64, (NN+63)/64, BB), dim3(256), 0, stream>>>(attgh, hg, resg, flagp, out);
  } else {
    k_cmix<<<dim3((NT+63)/64, BB), dim3(256), 0, stream>>>(Mc, x, flagp, mu_a, rs_a, Wf, out);
    k_graph<<<dim3(NN, BB), dim3(256), 0, stream>>>(lhsg, rhsg, adj, x, flagp, mu_a, rs_a, Wf, out);
    k_tbranch<<<dim3((NN+3)/4, BB), dim3(256), 0, stream>>>(x, flagp, mu_a, rs_a, Wf, attt, out, 0);
    k_res_final<<<dim3((NT+63)/64, 3, BB), dim3(256), 0, stream>>>(x, flagp, Wf, out);
  }
}